// Round 7
// baseline (364.018 us; speedup 1.0000x reference)
//
#include <hip/hip_runtime.h>

// ChunkedSelfAttention (RoPE + per-chunk causal SDPA), MI355X gfx950.
// R7: prepass (unchanged from R6) converts K (roped) + V^T to f16 in d_ws,
// pre-swizzled. Attention: 4-wave blocks, 64 q-rows/wave (2 groups of 32) so
// every K/V LDS fragment read feeds TWO MFMAs -> LDS bytes/MFMA halved.
// 1 wave/SIMD by design (VGPR ~300), R6's 512-block decode + sp loop.

typedef __attribute__((ext_vector_type(2)))  float     f32x2;
typedef __attribute__((ext_vector_type(4)))  float     f32x4;
typedef __attribute__((ext_vector_type(16))) float     f32x16;
typedef __attribute__((ext_vector_type(8)))  _Float16  f16x8;
typedef unsigned int   u32;
typedef unsigned short u16;
typedef __attribute__((ext_vector_type(4))) unsigned int u32x4;

#define MFMA(a, b, c) __builtin_amdgcn_mfma_f32_32x32x16_f16(a, b, c, 0, 0, 0)

constexpr int Ll = 4096;
constexpr float QSCALE = 0.08838834764831845f * 1.4426950408889634f; // 1/sqrt(128)*log2(e)

__device__ __forceinline__ f32x4 ld_f32x4(const void* p) { f32x4 v; __builtin_memcpy(&v, p, 16); return v; }
__device__ __forceinline__ f32x2 ld_f32x2(const void* p) { f32x2 v; __builtin_memcpy(&v, p, 8);  return v; }
__device__ __forceinline__ u32x4 ld_u32x4(const void* p) { u32x4 v; __builtin_memcpy(&v, p, 16); return v; }
__device__ __forceinline__ void  st_u32x4(void* p, u32x4 v) { __builtin_memcpy(p, &v, 16); }
__device__ __forceinline__ f16x8 ld_f16x8(const void* p) { f16x8 v; __builtin_memcpy(&v, p, 16); return v; }
__device__ __forceinline__ f16x8 ld_frag(const u32* dwp) {
  f16x8 v;
  __builtin_memcpy(&v, dwp, 8);
  __builtin_memcpy(((char*)&v) + 8, dwp + 2, 8);
  return v;
}
__device__ __forceinline__ u32 packh(_Float16 a, _Float16 b) {
  return (u32)__builtin_bit_cast(u16, a) | ((u32)__builtin_bit_cast(u16, b) << 16);
}
__device__ __forceinline__ u32 pkrtz(float a, float b) {
  auto v = __builtin_amdgcn_cvt_pkrtz(a, b);
  u32 r; __builtin_memcpy(&r, &v, 4); return r;
}

// ---- cos/sin table (verbatim R6) ----
__global__ void rope_table_k(const int* __restrict__ startp, float* __restrict__ tab) {
  int idx = blockIdx.x * 256 + threadIdx.x;
  int t = idx >> 6, hid = idx & 63;
  float a = (float)hid * (-0.14391156831212878f);
  float invf = expf(a);
  float ang = (float)(t + startp[0]) * invf;
  tab[2 * idx]     = cosf(ang);
  tab[2 * idx + 1] = sinf(ang);
}

// ---- prepass K (verbatim R6) ----
__global__ __launch_bounds__(256)
void prep_k_kernel(const float* __restrict__ Kg, const float* __restrict__ tab,
                   u32* __restrict__ Kh) {
  const int R    = blockIdx.x * 4 + (threadIdx.x >> 6);
  const int lane = threadIdx.x & 63;
  const int h  = R & 15;
  const int bt = R >> 4;
  const int b  = bt >> 12;
  const int t  = bt & 4095;
  const int c  = t >> 10;
  const int j  = (t >> 6) & 15;
  const int row = t & 63;
  const int GID = (b * 4 + c) * 16 + h;
  const int sw  = (row & 7) << 4;
  const int dc  = ((4 * lane) ^ sw) >> 1;
  f32x2 a = ld_f32x2(Kg + (size_t)R * 128 + dc);
  float p0 = __shfl_xor(a.x, 32);
  float p1 = __shfl_xor(a.y, 32);
  f32x4 cs = ld_f32x4(tab + (size_t)t * 128 + 2 * (dc & 63));
  const float sgn = (dc < 64) ? -1.0f : 1.0f;
  float o0 = a.x * cs.x + sgn * (p0 * cs.y);
  float o1 = a.y * cs.z + sgn * (p1 * cs.w);
  Kh[((size_t)(GID * 16 + j) * 64 + row) * 64 + lane] = packh((_Float16)o0, (_Float16)o1);
}

// ---- prepass V^T (verbatim R6) ----
__global__ __launch_bounds__(256)
void prep_vt_kernel(const float* __restrict__ Vg, u32* __restrict__ VT) {
  __shared__ __align__(16) u32 tile[4096];
  const int gj  = blockIdx.x;
  const int GID = gj >> 4, j = gj & 15;
  const int h = GID & 15, c = (GID >> 4) & 3, b = GID >> 6;
  const int tid = threadIdx.x;
  const size_t rowbase = ((size_t)(b * 4096 + c * 1024 + j * 64)) * 16 + h;
  const int k  = tid >> 2;
  const int dq = tid & 3;
  u16* t16 = (u16*)tile;
  #pragma unroll
  for (int it = 0; it < 8; ++it) {
    int dv0 = dq * 4 + 16 * it;
    f32x4 v4 = ld_f32x4(Vg + (rowbase + (size_t)k * 16) * 128 + dv0);
    #pragma unroll
    for (int u = 0; u < 4; ++u) {
      int dv = dv0 + u;
      int ci = k ^ ((dv & 7) << 3);
      t16[dv * 64 + ci] = __builtin_bit_cast(u16, (_Float16)v4[u]);
    }
  }
  __syncthreads();
  const u32* tsrc = tile + 16 * tid;
  u32* dst = VT + (size_t)gj * 4096 + 16 * tid;
  #pragma unroll
  for (int u = 0; u < 4; ++u) st_u32x4(dst + 4 * u, ld_u32x4(tsrc + 4 * u));
}

// ================= main attention: 4 waves, 64 q/wave =================
__global__ __launch_bounds__(256, 1)
void attn_f16_k(const float* __restrict__ Qg, const u32* __restrict__ Kh,
                const u32* __restrict__ VT, float* __restrict__ Og,
                const float* __restrict__ tab) {
  __shared__ __align__(16) u32 lds[2 * 8192];   // 64 KB, double-buffered

  const int bx  = blockIdx.x;            // R6 decode (known-pass)
  const int h   = bx & 15;
  const int p   = (bx >> 4) & 1;
  const int c   = (bx >> 5) & 3;
  const int b   = bx >> 7;
  const int tid = threadIdx.x;
  const int w   = tid >> 6;              // wave 0..3
  const int lane= tid & 63;
  const int l31 = lane & 31;
  const int lg2 = lane >> 5;

  const size_t cbase = (size_t)(b * Ll + c * 1024);
  const size_t hoff  = (size_t)h * 128;
  const int tb  = c * 1024;
  const int GID = (b * 4 + c) * 16 + h;
  const u32* khg = Kh + (size_t)GID * 16 * 4096;
  const u32* vtg = VT + (size_t)GID * 16 * 4096;

  u32x4 stg[8];
  auto issue = [&](int j) {
    #pragma unroll
    for (int i = 0; i < 8; ++i) {
      int ch = w * 8 + i;                // 32 chunks of 1 KB: 0..15 K, 16..31 VT
      const u32* src = (ch < 16) ? (khg + (size_t)j * 4096 + ch * 256 + 4 * lane)
                                 : (vtg + (size_t)j * 4096 + (ch - 16) * 256 + 4 * lane);
      stg[i] = ld_u32x4(src);
    }
  };
  auto store_stage = [&](int s) {
    u32* dst0 = lds + (size_t)s * 8192;
    #pragma unroll
    for (int i = 0; i < 8; ++i)
      st_u32x4(dst0 + (w * 8 + i) * 256 + 4 * lane, stg[i]);
  };

  // Q prologue helper: load 32 q-rows (lane column qrow), rope+scale -> f16
  auto loadq = [&](int qrow, f16x8* qh) {
    const float* qbase = Qg + (cbase + qrow) * 2048 + hoff;
    float xq[8][8];
    #pragma unroll
    for (int ds = 0; ds < 8; ++ds) {
      const float* ptr = qbase + ds * 16 + lg2 * 8;
      f32x4 v0 = ld_f32x4(ptr);
      f32x4 v1 = ld_f32x4(ptr + 4);
      xq[ds][0]=v0.x; xq[ds][1]=v0.y; xq[ds][2]=v0.z; xq[ds][3]=v0.w;
      xq[ds][4]=v1.x; xq[ds][5]=v1.y; xq[ds][6]=v1.z; xq[ds][7]=v1.w;
    }
    const float* trowq = tab + (size_t)(tb + qrow) * 128 + lg2 * 16;
    #pragma unroll
    for (int ds = 0; ds < 4; ++ds) {
      #pragma unroll
      for (int i2 = 0; i2 < 4; ++i2) {
        f32x4 cs = ld_f32x4(trowq + ds * 32 + i2 * 4);
        int i0 = 2 * i2;
        float a0 = xq[ds][i0],     b0 = xq[ds + 4][i0];
        xq[ds][i0]     = a0 * cs.x - b0 * cs.y;
        xq[ds + 4][i0] = b0 * cs.x + a0 * cs.y;
        float a1 = xq[ds][i0 + 1], b1 = xq[ds + 4][i0 + 1];
        xq[ds][i0 + 1]     = a1 * cs.z - b1 * cs.w;
        xq[ds + 4][i0 + 1] = b1 * cs.z + a1 * cs.w;
      }
    }
    #pragma unroll
    for (int ds = 0; ds < 8; ++ds)
      #pragma unroll
      for (int i = 0; i < 8; ++i)
        qh[ds][i] = (_Float16)(xq[ds][i] * QSCALE);
  };

  #pragma unroll 1
  for (int sp = 0; sp < 2; ++sp) {
    const int qs = sp ? p : (3 - p);            // heavy strip first
    const int qb = qs * 256 + w * 64;           // wave q-base (2 groups of 32)

    f16x8 qhA[8], qhB[8];
    loadq(qb + l31, qhA);
    loadq(qb + 32 + l31, qhB);

    f32x16 OA[4], OB[4];
    #pragma unroll
    for (int n = 0; n < 4; ++n) { OA[n] = (f32x16)0.0f; OB[n] = (f32x16)0.0f; }
    float m2A = -1e30f, lsA = 0.0f, m2B = -1e30f, lsB = 0.0f;
    const int j0 = 4 * qs + w;       // wave's diagonal tile
    const int nt = 4 * (qs + 1);

    issue(0);
    store_stage(0);
    __syncthreads();

    for (int j = 0; j < nt; ++j) {
      const int s = j & 1;
      const bool more = (j + 1 < nt);
      if (more) issue(j + 1);

      if (j <= j0) {
        const bool diag = (j == j0);
        const u32* KB  = lds + (size_t)s * 8192;
        const u32* VB  = KB + 4096;
        const u32* kr0 = KB + (size_t)l31 * 64;
        const u32* kr1 = kr0 + 2048;
        const int  swk = (l31 & 7) << 2;

        // ---- QK^T: shared K fragment feeds both q-groups ----
        f32x16 S0A = (f32x16)0.0f, S1A = (f32x16)0.0f;
        f32x16 S0B = (f32x16)0.0f, S1B = (f32x16)0.0f;
        #pragma unroll
        for (int ds = 0; ds < 8; ++ds) {
          int dc = (8 * ds + 4 * lg2) ^ swk;
          f16x8 k0 = ld_f16x8(kr0 + dc);
          f16x8 k1 = ld_f16x8(kr1 + dc);
          S0A = MFMA(k0, qhA[ds], S0A);
          S0B = MFMA(k0, qhB[ds], S0B);
          if (!diag) S1A = MFMA(k1, qhA[ds], S1A);
          S1B = MFMA(k1, qhB[ds], S1B);
        }

        // ---- causal mask on the diagonal tile ----
        if (diag) {
          #pragma unroll
          for (int r = 0; r < 16; ++r) {
            int crow = (r & 3) + 8 * (r >> 2) + 4 * lg2;
            if (crow > l31) { S0A[r] = -1e30f; S1B[r] = -1e30f; }
          }
        }

        // ---- online softmax per group (base-2, deferred rescale) ----
        u32 UA[16], UB[16];
        auto softmax = [&](f32x16& S0, f32x16& S1, bool full, float& m2,
                           float& lsum, u32* U, f32x16* O) {
          float tm = S0[0];
          #pragma unroll
          for (int r = 1; r < 16; ++r) tm = fmaxf(tm, S0[r]);
          if (full) {
            #pragma unroll
            for (int r = 0; r < 16; ++r) tm = fmaxf(tm, S1[r]);
          }
          tm = fmaxf(tm, __shfl_xor(tm, 32));
          if (!__all(tm <= m2 + 8.0f)) {
            float m2n = fmaxf(m2, tm);
            float fac = exp2f(m2 - m2n);
            lsum *= fac;
            #pragma unroll
            for (int r = 0; r < 16; ++r) {
              int rq = (r & 3) + 8 * (r >> 2) + 4 * lg2;
              float fr = __shfl(fac, rq);
              O[0][r] *= fr; O[1][r] *= fr; O[2][r] *= fr; O[3][r] *= fr;
            }
            m2 = m2n;
          }
          float ps = 0.0f;
          #pragma unroll
          for (int t = 0; t < 8; ++t) {
            float e0 = exp2f(S0[2 * t]     - m2);
            float e1 = exp2f(S0[2 * t + 1] - m2);
            U[t] = pkrtz(e0, e1);
            ps += e0 + e1;
          }
          if (full) {
            #pragma unroll
            for (int t = 0; t < 8; ++t) {
              float e0 = exp2f(S1[2 * t]     - m2);
              float e1 = exp2f(S1[2 * t + 1] - m2);
              U[8 + t] = pkrtz(e0, e1);
              ps += e0 + e1;
            }
          }
          ps += __shfl_xor(ps, 32);
          lsum += ps;
        };
        softmax(S0A, S1A, !diag, m2A, lsA, UA, OA);
        softmax(S0B, S1B, true,  m2B, lsB, UB, OB);

        // ---- PV: shared V fragment feeds both groups ----
        #pragma unroll
        for (int ks = 0; ks < 4; ++ks) {
          const bool aAct = !(diag && ks >= 2);
          f16x8 paA, paB;
          {
            u32 a0 = UB[4 * ks + 0], a1 = UB[4 * ks + 1];
            u32 b0 = UB[4 * ks + 2], b1 = UB[4 * ks + 3];
            asm("v_permlane32_swap_b32 %0, %1" : "+v"(a0), "+v"(b0));
            asm("v_permlane32_swap_b32 %0, %1" : "+v"(a1), "+v"(b1));
            u32x4 t4; t4.x = a0; t4.y = a1; t4.z = b0; t4.w = b1;
            paB = __builtin_bit_cast(f16x8, t4);
          }
          if (aAct) {
            u32 a0 = UA[4 * ks + 0], a1 = UA[4 * ks + 1];
            u32 b0 = UA[4 * ks + 2], b1 = UA[4 * ks + 3];
            asm("v_permlane32_swap_b32 %0, %1" : "+v"(a0), "+v"(b0));
            asm("v_permlane32_swap_b32 %0, %1" : "+v"(a1), "+v"(b1));
            u32x4 t4; t4.x = a0; t4.y = a1; t4.z = b0; t4.w = b1;
            paA = __builtin_bit_cast(f16x8, t4);
          }
          int dcv = (8 * ks + 4 * lg2) ^ swk;
          #pragma unroll
          for (int n = 0; n < 4; ++n) {
            f16x8 vf = ld_f16x8(VB + (size_t)(32 * n + l31) * 32 + dcv);
            if (aAct) OA[n] = MFMA(paA, vf, OA[n]);
            OB[n] = MFMA(paB, vf, OB[n]);
          }
        }
      }

      if (more) store_stage(s ^ 1);
      __syncthreads();
    }

    // ---------- epilogue (per group) ----------
    auto epi = [&](float lsum, f32x16* O, int qbg) {
      float inv = 1.0f / lsum;
      #pragma unroll
      for (int r = 0; r < 16; ++r) {
        int rq = (r & 3) + 8 * (r >> 2) + 4 * lg2;
        float fi = __shfl(inv, rq);
        float* orow = Og + (cbase + qbg + rq) * 2048 + hoff + l31;
        orow[0]  = O[0][r] * fi;
        orow[32] = O[1][r] * fi;
        orow[64] = O[2][r] * fi;
        orow[96] = O[3][r] * fi;
      }
    };
    epi(lsA, OA, qb);
    epi(lsB, OB, qb + 32);
  }
}

// ================= fallback (R6/R4, passed) =================
#define KSTR 66
#define VSTR 34
#define KBUF (64 * KSTR)
#define VBUF (128 * VSTR)
#define STG  (KBUF + VBUF)

__global__ __launch_bounds__(512, 2)
void chunked_attn_fb(const float* __restrict__ Qg, const float* __restrict__ Kg,
                     const float* __restrict__ Vg, float* __restrict__ Og,
                     const float* __restrict__ tab) {
  __shared__ __align__(16) u32 lds[2 * STG];

  const int bx  = blockIdx.x;
  const int h   = bx & 15;
  const int p   = (bx >> 4) & 1;
  const int c   = (bx >> 5) & 3;
  const int b   = bx >> 7;
  const int tid = threadIdx.x;
  const int w   = tid >> 6;
  const int lane= tid & 63;
  const int l31 = lane & 31;
  const int lg2 = lane >> 5;

  const size_t cbase = (size_t)(b * Ll + c * 1024);
  const size_t hoff  = (size_t)h * 128;
  const int tb = c * 1024;

  f32x2 pk[8], pva[4], pvb[4];

  auto issue = [&](int j) {
    const float* kb_ = Kg + (cbase + (size_t)j * 64) * 2048 + hoff;
    const float* vb_ = Vg + (cbase + (size_t)j * 64) * 2048 + hoff;
    #pragma unroll
    for (int r = 0; r < 8; ++r)
      pk[r] = ld_f32x2(kb_ + (size_t)(8 * w + r) * 2048 + 2 * lane);
    #pragma unroll
    for (int rp = 0; rp < 4; ++rp) {
      const float* vr = vb_ + (size_t)(8 * w + 2 * rp) * 2048 + 2 * lane;
      pva[rp] = ld_f32x2(vr);
      pvb[rp] = ld_f32x2(vr + 2048);
    }
  };

  auto xform = [&](int j, int s) {
    u32* KB = lds + s * STG;
    u32* VB = KB + KBUF;
    const float* tbase = tab + (size_t)(tb + j * 64) * 128 + 4 * l31;
    f32x4 cs[8];
    #pragma unroll
    for (int r = 0; r < 8; ++r)
      cs[r] = ld_f32x4(tbase + (size_t)(8 * w + r) * 128);
    const float sgn = (lane < 32) ? -1.0f : 1.0f;
    #pragma unroll
    for (int r = 0; r < 8; ++r) {
      float a0 = pk[r].x, a1 = pk[r].y;
      float p0 = __shfl_xor(a0, 32), p1 = __shfl_xor(a1, 32);
      float o0 = a0 * cs[r].x + sgn * (p0 * cs[r].y);
      float o1 = a1 * cs[r].z + sgn * (p1 * cs[r].w);
      KB[(8 * w + r) * KSTR + lane] = packh((_Float16)o0, (_Float16)o1);
    }
    #pragma unroll
    for (int rp = 0; rp < 4; ++rp) {
      int kp = 4 * w + rp;
      VB[(2 * lane) * VSTR + kp]     = packh((_Float16)pva[rp].x, (_Float16)pvb[rp].x);
      VB[(2 * lane + 1) * VSTR + kp] = packh((_Float16)pva[rp].y, (_Float16)pvb[rp].y);
    }
  };

  #pragma unroll 1
  for (int sp = 0; sp < 2; ++sp) {
    const int qs = sp ? p : (3 - p);
    const int qrow = qs * 256 + w * 32 + l31;

    const float* qbase = Qg + (cbase + qrow) * 2048 + hoff;
    float xq[8][8];
    #pragma unroll
    for (int ds = 0; ds < 8; ++ds) {
      const float* ptr = qbase + ds * 16 + lg2 * 8;
      f32x4 v0 = ld_f32x4(ptr);
      f32x4 v1 = ld_f32x4(ptr + 4);
      xq[ds][0]=v0.x; xq[ds][1]=v0.y; xq[ds][2]=v0.z; xq[ds][3]=v0.w;
      xq[ds][4]=v1.x; xq[ds][5]=v1.y; xq[ds][6]=v1.z; xq[ds][7]=v1.w;
    }
    const float* trowq = tab + (size_t)(tb + qrow) * 128 + lg2 * 16;
    #pragma unroll
    for (int ds = 0; ds < 4; ++ds) {
      #pragma unroll
      for (int i2 = 0; i2 < 4; ++i2) {
        f32x4 cs = ld_f32x4(trowq + ds * 32 + i2 * 4);
        int i0 = 2 * i2;
        float a0 = xq[ds][i0],     b0 = xq[ds + 4][i0];
        xq[ds][i0]     = a0 * cs.x - b0 * cs.y;
        xq[ds + 4][i0] = b0 * cs.x + a0 * cs.y;
        float a1 = xq[ds][i0 + 1], b1 = xq[ds + 4][i0 + 1];
        xq[ds][i0 + 1]     = a1 * cs.z - b1 * cs.w;
        xq[ds + 4][i0 + 1] = b1 * cs.z + a1 * cs.w;
      }
    }
    f16x8 qh[8];
    #pragma unroll
    for (int ds = 0; ds < 8; ++ds)
      #pragma unroll
      for (int i = 0; i < 8; ++i)
        qh[ds][i] = (_Float16)(xq[ds][i] * QSCALE);

    f32x16 O[4];
    #pragma unroll
    for (int n = 0; n < 4; ++n) O[n] = (f32x16)0.0f;
    float m2 = -1e30f, lsum = 0.0f;
    const int  nt    = 4 * (qs + 1);
    const int  jmaxw = 4 * qs + (w >> 1);
    const bool oddw  = w & 1;

    issue(0);
    xform(0, 0);
    __syncthreads();

    for (int j = 0; j < nt; ++j) {
      const int s = j & 1;
      const bool more = (j + 1 < nt);
      if (more) issue(j + 1);

      if (j <= jmaxw) {
        const bool full = oddw || (j < jmaxw);
        const u32* KB = lds + s * STG;
        const u32* VB = KB + KBUF;
        const u32* kr0 = KB + (size_t)l31 * KSTR + lg2 * 4;
        const u32* kr1 = kr0 + (size_t)32 * KSTR;

        f32x16 S0 = (f32x16)0.0f, S1 = (f32x16)0.0f;
        __builtin_amdgcn_s_setprio(1);
        #pragma unroll
        for (int ds = 0; ds < 8; ++ds) {
          S0 = MFMA(ld_frag(kr0 + ds * 8), qh[ds], S0);
          if (full) S1 = MFMA(ld_frag(kr1 + ds * 8), qh[ds], S1);
        }
        __builtin_amdgcn_s_setprio(0);

        if (j == jmaxw) {
          #pragma unroll
          for (int r = 0; r < 16; ++r) {
            int crow = (r & 3) + 8 * (r >> 2) + 4 * lg2;
            if (crow > l31) { if (oddw) S1[r] = -1e30f; else S0[r] = -1e30f; }
          }
        }

        float tm = S0[0];
        #pragma unroll
        for (int r = 1; r < 16; ++r) tm = fmaxf(tm, S0[r]);
        if (full) {
          #pragma unroll
          for (int r = 0; r < 16; ++r) tm = fmaxf(tm, S1[r]);
        }
        tm = fmaxf(tm, __shfl_xor(tm, 32));
        if (!__all(tm <= m2 + 8.0f)) {
          float m2n = fmaxf(m2, tm);
          float fac = exp2f(m2 - m2n);
          lsum *= fac;
          #pragma unroll
          for (int r = 0; r < 16; ++r) {
            int rq = (r & 3) + 8 * (r >> 2) + 4 * lg2;
            float fr = __shfl(fac, rq);
            O[0][r] *= fr; O[1][r] *= fr; O[2][r] *= fr; O[3][r] *= fr;
          }
          m2 = m2n;
        }
        u32 U[16];
        float ps = 0.0f;
        #pragma unroll
        for (int t = 0; t < 8; ++t) {
          float e0 = exp2f(S0[2 * t]     - m2);
          float e1 = exp2f(S0[2 * t + 1] - m2);
          U[t] = packh((_Float16)e0, (_Float16)e1);
          ps += e0 + e1;
        }
        if (full) {
          #pragma unroll
          for (int t = 0; t < 8; ++t) {
            float e0 = exp2f(S1[2 * t]     - m2);
            float e1 = exp2f(S1[2 * t + 1] - m2);
            U[8 + t] = packh((_Float16)e0, (_Float16)e1);
            ps += e0 + e1;
          }
        }
        ps += __shfl_xor(ps, 32);
        lsum += ps;

        __builtin_amdgcn_s_setprio(1);
        #pragma unroll
        for (int ks = 0; ks < 4; ++ks) {
          if (ks >= 2 && !full) continue;
          u32 a0 = U[4 * ks + 0], a1 = U[4 * ks + 1];
          u32 b0 = U[4 * ks + 2], b1 = U[4 * ks + 3];
          asm("v_permlane32_swap_b32 %0, %1" : "+v"(a0), "+v"(b0));
          asm("v_permlane32_swap_b32 %0, %1" : "+v"(a1), "+v"(b1));
          u32x4 t4; t4.x = a0; t4.y = a1; t4.z = b0; t4.w = b1;
          f16x8 pa = __builtin_bit_cast(f16x8, t4);
          #pragma unroll
          for (int n = 0; n < 4; ++n) {
            const u32* vp = VB + (size_t)(32 * n + l31) * VSTR + 8 * ks + 4 * lg2;
            O[n] = MFMA(pa, ld_frag(vp), O[n]);
          }
        }
        __builtin_amdgcn_s_setprio(0);
      }

      if (more) xform(j + 1, s ^ 1);
      __syncthreads();
    }

    float inv = 1.0f / lsum;
    #pragma unroll
    for (int r = 0; r < 16; ++r) {
      int rq = (r & 3) + 8 * (r >> 2) + 4 * lg2;
      float fi = __shfl(inv, rq);
      float* orow = Og + (cbase + qs * 256 + w * 32 + rq) * 2048 + hoff + l31;
      orow[0]  = O[0][r] * fi;
      orow[32] = O[1][r] * fi;
      orow[64] = O[2][r] * fi;
      orow[96] = O[3][r] * fi;
    }
  }
}

extern "C" void kernel_launch(void* const* d_in, const int* in_sizes, int n_in,
                              void* d_out, int out_size, void* d_ws, size_t ws_size,
                              hipStream_t stream) {
  const float* q = (const float*)d_in[0];
  const float* k = (const float*)d_in[1];
  const float* v = (const float*)d_in[2];
  const int* start = (const int*)d_in[3];
  float* out = (float*)d_out;

  float* tab = (float*)d_ws;                          // 2 MB
  const size_t KH_OFFB = 2u * 1024 * 1024;            // 64 MB
  const size_t VT_OFFB = KH_OFFB + 64u * 1024 * 1024; // 64 MB
  const size_t NEED = VT_OFFB + 64u * 1024 * 1024;    // 130 MB total

  rope_table_k<<<dim3(1024), dim3(256), 0, stream>>>(start, tab);

  if (ws_size >= NEED) {
    u32* Kh = (u32*)((char*)d_ws + KH_OFFB);
    u32* VT = (u32*)((char*)d_ws + VT_OFFB);
    prep_k_kernel<<<dim3(65536), dim3(256), 0, stream>>>(k, tab, Kh);
    prep_vt_kernel<<<dim3(4096), dim3(256), 0, stream>>>(v, VT);
    attn_f16_k<<<dim3(512), dim3(256), 0, stream>>>(q, Kh, VT, out, tab);
  } else {
    chunked_attn_fb<<<dim3(512), dim3(512), 0, stream>>>(q, k, v, out, tab);
  }
}

// Round 9
// 293.371 us; speedup vs baseline: 1.2408x; 1.2408x over previous
//
#include <hip/hip_runtime.h>

// ChunkedSelfAttention (RoPE + per-chunk causal SDPA), MI355X gfx950.
// R9: R6 skeleton verbatim (known-pass: attn math, prep kernels, decode,
// online softmax w/ deferred rescale) with ONE change: staging goes through
// __builtin_amdgcn_global_load_lds (16B/lane direct DMA) instead of
// register round-trip. Layouts linear by construction (swizzle pre-baked
// in global). Math bit-identical to R6.

typedef __attribute__((ext_vector_type(2)))  float     f32x2;
typedef __attribute__((ext_vector_type(4)))  float     f32x4;
typedef __attribute__((ext_vector_type(16))) float     f32x16;
typedef __attribute__((ext_vector_type(8)))  _Float16  f16x8;
typedef unsigned int   u32;
typedef unsigned short u16;
typedef __attribute__((ext_vector_type(4))) unsigned int u32x4;

typedef __attribute__((address_space(1))) const u32 as1c_u32;
typedef __attribute__((address_space(3))) u32       as3_u32;

#define MFMA(a, b, c) __builtin_amdgcn_mfma_f32_32x32x16_f16(a, b, c, 0, 0, 0)

constexpr int Ll = 4096;
constexpr float QSCALE = 0.08838834764831845f * 1.4426950408889634f; // 1/sqrt(128)*log2(e)

__device__ __forceinline__ f32x4 ld_f32x4(const void* p) { f32x4 v; __builtin_memcpy(&v, p, 16); return v; }
__device__ __forceinline__ f32x2 ld_f32x2(const void* p) { f32x2 v; __builtin_memcpy(&v, p, 8);  return v; }
__device__ __forceinline__ u32x4 ld_u32x4(const void* p) { u32x4 v; __builtin_memcpy(&v, p, 16); return v; }
__device__ __forceinline__ void  st_u32x4(void* p, u32x4 v) { __builtin_memcpy(p, &v, 16); }
__device__ __forceinline__ f16x8 ld_f16x8(const void* p) { f16x8 v; __builtin_memcpy(&v, p, 16); return v; }
__device__ __forceinline__ f16x8 ld_frag(const u32* dwp) {
  f16x8 v;
  __builtin_memcpy(&v, dwp, 8);
  __builtin_memcpy(((char*)&v) + 8, dwp + 2, 8);
  return v;
}
__device__ __forceinline__ u32 packh(_Float16 a, _Float16 b) {
  return (u32)__builtin_bit_cast(u16, a) | ((u32)__builtin_bit_cast(u16, b) << 16);
}

// ---- cos/sin table (verbatim R6) ----
__global__ void rope_table_k(const int* __restrict__ startp, float* __restrict__ tab) {
  int idx = blockIdx.x * 256 + threadIdx.x;
  int t = idx >> 6, hid = idx & 63;
  float a = (float)hid * (-0.14391156831212878f);
  float invf = expf(a);
  float ang = (float)(t + startp[0]) * invf;
  tab[2 * idx]     = cosf(ang);
  tab[2 * idx + 1] = sinf(ang);
}

// ---- prepass K (verbatim R6) ----
__global__ __launch_bounds__(256)
void prep_k_kernel(const float* __restrict__ Kg, const float* __restrict__ tab,
                   u32* __restrict__ Kh) {
  const int R    = blockIdx.x * 4 + (threadIdx.x >> 6);
  const int lane = threadIdx.x & 63;
  const int h  = R & 15;
  const int bt = R >> 4;
  const int b  = bt >> 12;
  const int t  = bt & 4095;
  const int c  = t >> 10;
  const int j  = (t >> 6) & 15;
  const int row = t & 63;
  const int GID = (b * 4 + c) * 16 + h;
  const int sw  = (row & 7) << 4;
  const int dc  = ((4 * lane) ^ sw) >> 1;
  f32x2 a = ld_f32x2(Kg + (size_t)R * 128 + dc);
  float p0 = __shfl_xor(a.x, 32);
  float p1 = __shfl_xor(a.y, 32);
  f32x4 cs = ld_f32x4(tab + (size_t)t * 128 + 2 * (dc & 63));
  const float sgn = (dc < 64) ? -1.0f : 1.0f;
  float o0 = a.x * cs.x + sgn * (p0 * cs.y);
  float o1 = a.y * cs.z + sgn * (p1 * cs.w);
  Kh[((size_t)(GID * 16 + j) * 64 + row) * 64 + lane] = packh((_Float16)o0, (_Float16)o1);
}

// ---- prepass V^T (verbatim R6) ----
__global__ __launch_bounds__(256)
void prep_vt_kernel(const float* __restrict__ Vg, u32* __restrict__ VT) {
  __shared__ __align__(16) u32 tile[4096];
  const int gj  = blockIdx.x;
  const int GID = gj >> 4, j = gj & 15;
  const int h = GID & 15, c = (GID >> 4) & 3, b = GID >> 6;
  const int tid = threadIdx.x;
  const size_t rowbase = ((size_t)(b * 4096 + c * 1024 + j * 64)) * 16 + h;
  const int k  = tid >> 2;
  const int dq = tid & 3;
  u16* t16 = (u16*)tile;
  #pragma unroll
  for (int it = 0; it < 8; ++it) {
    int dv0 = dq * 4 + 16 * it;
    f32x4 v4 = ld_f32x4(Vg + (rowbase + (size_t)k * 16) * 128 + dv0);
    #pragma unroll
    for (int u = 0; u < 4; ++u) {
      int dv = dv0 + u;
      int ci = k ^ ((dv & 7) << 3);
      t16[dv * 64 + ci] = __builtin_bit_cast(u16, (_Float16)v4[u]);
    }
  }
  __syncthreads();
  const u32* tsrc = tile + 16 * tid;
  u32* dst = VT + (size_t)gj * 4096 + 16 * tid;
  #pragma unroll
  for (int u = 0; u < 4; ++u) st_u32x4(dst + 4 * u, ld_u32x4(tsrc + 4 * u));
}

// ================= main attention (R6 skeleton + global_load_lds staging) =================
__global__ __launch_bounds__(512, 2)
void attn_f16_k(const float* __restrict__ Qg, const u32* __restrict__ Kh,
                const u32* __restrict__ VT, float* __restrict__ Og,
                const float* __restrict__ tab) {
  __shared__ __align__(16) u32 lds[2 * 8192];   // 64 KB, double-buffered

  const int bx  = blockIdx.x;            // R6 decode (known-pass)
  const int h   = bx & 15;
  const int p   = (bx >> 4) & 1;
  const int c   = (bx >> 5) & 3;
  const int b   = bx >> 7;
  const int tid = threadIdx.x;
  const int w   = tid >> 6;
  const int lane= tid & 63;
  const int l31 = lane & 31;
  const int lg2 = lane >> 5;

  const size_t cbase = (size_t)(b * Ll + c * 1024);
  const size_t hoff  = (size_t)h * 128;
  const int tb  = c * 1024;
  const int GID = (b * 4 + c) * 16 + h;
  const u32* khg = Kh + (size_t)GID * 16 * 4096;
  const u32* vtg = VT + (size_t)GID * 16 * 4096;

  // async staging: per wave 4 chunks of 1 KB; LDS dest is wave-uniform base,
  // HW adds lane*16; global src is per-lane (layout linear on both sides).
  auto stage_async = [&](int j, int s) {
    u32* dst0 = lds + (size_t)s * 8192;
    #pragma unroll
    for (int i = 0; i < 4; ++i) {
      int ch = w + 8 * i;                // 0..15 K, 16..31 VT
      const u32* src = (ch < 16) ? (khg + (size_t)j * 4096 + ch * 256 + 4 * lane)
                                 : (vtg + (size_t)j * 4096 + (ch - 16) * 256 + 4 * lane);
      __builtin_amdgcn_global_load_lds((as1c_u32*)src, (as3_u32*)(dst0 + ch * 256),
                                       16, 0, 0);
    }
  };

  #pragma unroll 1
  for (int sp = 0; sp < 2; ++sp) {
    const int qs = sp ? p : (3 - p);            // heavy strip first
    const int qrow = qs * 256 + w * 32 + l31;

    // ---------- Q prologue: load f32, rope, scale, f16 (verbatim R6) ----------
    const float* qbase = Qg + (cbase + qrow) * 2048 + hoff;
    float xq[8][8];
    #pragma unroll
    for (int ds = 0; ds < 8; ++ds) {
      const float* ptr = qbase + ds * 16 + lg2 * 8;
      f32x4 v0 = ld_f32x4(ptr);
      f32x4 v1 = ld_f32x4(ptr + 4);
      xq[ds][0]=v0.x; xq[ds][1]=v0.y; xq[ds][2]=v0.z; xq[ds][3]=v0.w;
      xq[ds][4]=v1.x; xq[ds][5]=v1.y; xq[ds][6]=v1.z; xq[ds][7]=v1.w;
    }
    const float* trowq = tab + (size_t)(tb + qrow) * 128 + lg2 * 16;
    #pragma unroll
    for (int ds = 0; ds < 4; ++ds) {
      #pragma unroll
      for (int i2 = 0; i2 < 4; ++i2) {
        f32x4 cs = ld_f32x4(trowq + ds * 32 + i2 * 4);
        int i0 = 2 * i2;
        float a0 = xq[ds][i0],     b0 = xq[ds + 4][i0];
        xq[ds][i0]     = a0 * cs.x - b0 * cs.y;
        xq[ds + 4][i0] = b0 * cs.x + a0 * cs.y;
        float a1 = xq[ds][i0 + 1], b1 = xq[ds + 4][i0 + 1];
        xq[ds][i0 + 1]     = a1 * cs.z - b1 * cs.w;
        xq[ds + 4][i0 + 1] = b1 * cs.z + a1 * cs.w;
      }
    }
    f16x8 qh[8];
    #pragma unroll
    for (int ds = 0; ds < 8; ++ds)
      #pragma unroll
      for (int i = 0; i < 8; ++i)
        qh[ds][i] = (_Float16)(xq[ds][i] * QSCALE);

    // ---------- state ----------
    f32x16 O[4];
    #pragma unroll
    for (int n = 0; n < 4; ++n) O[n] = (f32x16)0.0f;
    float m2 = -1e30f, lsum = 0.0f;
    const int  nt    = 4 * (qs + 1);
    const int  jmaxw = 4 * qs + (w >> 1);
    const bool oddw  = w & 1;

    stage_async(0, 0);
    __syncthreads();

    for (int j = 0; j < nt; ++j) {
      const int s = j & 1;
      const bool more = (j + 1 < nt);
      if (more) stage_async(j + 1, s ^ 1);   // DMA flies under compute

      if (j <= jmaxw) {
        const bool full = oddw || (j < jmaxw);
        const u32* KB = lds + (size_t)s * 8192;
        const u32* VB = KB + 4096;
        const u32* kr0 = KB + (size_t)l31 * 64;
        const u32* kr1 = kr0 + 32 * 64;
        const int  swk = (l31 & 7) << 2;      // dword-col XOR

        // ---- QK^T (swapped): S^T[k][q] = K . Q^T ----
        f32x16 S0 = (f32x16)0.0f, S1 = (f32x16)0.0f;
        __builtin_amdgcn_s_setprio(1);
        #pragma unroll
        for (int ds = 0; ds < 8; ++ds) {
          int dc = (8 * ds + 4 * lg2) ^ swk;
          S0 = MFMA(ld_f16x8(kr0 + dc), qh[ds], S0);
          if (full) S1 = MFMA(ld_f16x8(kr1 + dc), qh[ds], S1);
        }
        __builtin_amdgcn_s_setprio(0);

        // ---- causal mask (diagonal tile only) ----
        if (j == jmaxw) {
          #pragma unroll
          for (int r = 0; r < 16; ++r) {
            int crow = (r & 3) + 8 * (r >> 2) + 4 * lg2;
            if (crow > l31) { if (oddw) S1[r] = -1e30f; else S0[r] = -1e30f; }
          }
        }

        // ---- online softmax (base-2), T13 deferred rescale (verbatim R6) ----
        float tm = S0[0];
        #pragma unroll
        for (int r = 1; r < 16; ++r) tm = fmaxf(tm, S0[r]);
        if (full) {
          #pragma unroll
          for (int r = 0; r < 16; ++r) tm = fmaxf(tm, S1[r]);
        }
        tm = fmaxf(tm, __shfl_xor(tm, 32));
        if (!__all(tm <= m2 + 8.0f)) {
          float m2n = fmaxf(m2, tm);
          float fac = exp2f(m2 - m2n);
          lsum *= fac;
          #pragma unroll
          for (int r = 0; r < 16; ++r) {
            int rq = (r & 3) + 8 * (r >> 2) + 4 * lg2;
            float fr = __shfl(fac, rq);
            O[0][r] *= fr; O[1][r] *= fr; O[2][r] *= fr; O[3][r] *= fr;
          }
          m2 = m2n;
        }
        u32 U[16];
        float ps = 0.0f;
        #pragma unroll
        for (int t = 0; t < 8; ++t) {
          float e0 = exp2f(S0[2 * t]     - m2);
          float e1 = exp2f(S0[2 * t + 1] - m2);
          U[t] = packh((_Float16)e0, (_Float16)e1);
          ps += e0 + e1;
        }
        if (full) {
          #pragma unroll
          for (int t = 0; t < 8; ++t) {
            float e0 = exp2f(S1[2 * t]     - m2);
            float e1 = exp2f(S1[2 * t + 1] - m2);
            U[8 + t] = packh((_Float16)e0, (_Float16)e1);
            ps += e0 + e1;
          }
        }
        ps += __shfl_xor(ps, 32);
        lsum += ps;

        // ---- PV: P fragments in-register via permlane32_swap ----
        __builtin_amdgcn_s_setprio(1);
        #pragma unroll
        for (int ks = 0; ks < 4; ++ks) {
          if (ks >= 2 && !full) continue;
          u32 a0 = U[4 * ks + 0], a1 = U[4 * ks + 1];
          u32 b0 = U[4 * ks + 2], b1 = U[4 * ks + 3];
          asm("v_permlane32_swap_b32 %0, %1" : "+v"(a0), "+v"(b0));
          asm("v_permlane32_swap_b32 %0, %1" : "+v"(a1), "+v"(b1));
          u32x4 t4; t4.x = a0; t4.y = a1; t4.z = b0; t4.w = b1;
          f16x8 pa = __builtin_bit_cast(f16x8, t4);
          int dcv = (8 * ks + 4 * lg2) ^ swk;
          #pragma unroll
          for (int n = 0; n < 4; ++n) {
            O[n] = MFMA(pa, ld_f16x8(VB + (size_t)(32 * n + l31) * 32 + dcv), O[n]);
          }
        }
        __builtin_amdgcn_s_setprio(0);
      }

      __syncthreads();
    }

    // ---------- epilogue ----------
    float inv = 1.0f / lsum;
    #pragma unroll
    for (int r = 0; r < 16; ++r) {
      int rq = (r & 3) + 8 * (r >> 2) + 4 * lg2;
      float fi = __shfl(inv, rq);
      float* orow = Og + (cbase + qs * 256 + w * 32 + rq) * 2048 + hoff + l31;
      orow[0]  = O[0][r] * fi;
      orow[32] = O[1][r] * fi;
      orow[64] = O[2][r] * fi;
      orow[96] = O[3][r] * fi;
    }
  }
}

// ================= fallback (R4/R6, passed) =================
#define KSTR 66
#define VSTR 34
#define KBUF (64 * KSTR)
#define VBUF (128 * VSTR)
#define STG  (KBUF + VBUF)

__global__ __launch_bounds__(512, 2)
void chunked_attn_fb(const float* __restrict__ Qg, const float* __restrict__ Kg,
                     const float* __restrict__ Vg, float* __restrict__ Og,
                     const float* __restrict__ tab) {
  __shared__ __align__(16) u32 lds[2 * STG];

  const int bx  = blockIdx.x;
  const int h   = bx & 15;
  const int p   = (bx >> 4) & 1;
  const int c   = (bx >> 5) & 3;
  const int b   = bx >> 7;
  const int tid = threadIdx.x;
  const int w   = tid >> 6;
  const int lane= tid & 63;
  const int l31 = lane & 31;
  const int lg2 = lane >> 5;

  const size_t cbase = (size_t)(b * Ll + c * 1024);
  const size_t hoff  = (size_t)h * 128;
  const int tb = c * 1024;

  f32x2 pk[8], pva[4], pvb[4];

  auto issue = [&](int j) {
    const float* kb_ = Kg + (cbase + (size_t)j * 64) * 2048 + hoff;
    const float* vb_ = Vg + (cbase + (size_t)j * 64) * 2048 + hoff;
    #pragma unroll
    for (int r = 0; r < 8; ++r)
      pk[r] = ld_f32x2(kb_ + (size_t)(8 * w + r) * 2048 + 2 * lane);
    #pragma unroll
    for (int rp = 0; rp < 4; ++rp) {
      const float* vr = vb_ + (size_t)(8 * w + 2 * rp) * 2048 + 2 * lane;
      pva[rp] = ld_f32x2(vr);
      pvb[rp] = ld_f32x2(vr + 2048);
    }
  };

  auto xform = [&](int j, int s) {
    u32* KB = lds + s * STG;
    u32* VB = KB + KBUF;
    const float* tbase = tab + (size_t)(tb + j * 64) * 128 + 4 * l31;
    f32x4 cs[8];
    #pragma unroll
    for (int r = 0; r < 8; ++r)
      cs[r] = ld_f32x4(tbase + (size_t)(8 * w + r) * 128);
    const float sgn = (lane < 32) ? -1.0f : 1.0f;
    #pragma unroll
    for (int r = 0; r < 8; ++r) {
      float a0 = pk[r].x, a1 = pk[r].y;
      float p0 = __shfl_xor(a0, 32), p1 = __shfl_xor(a1, 32);
      float o0 = a0 * cs[r].x + sgn * (p0 * cs[r].y);
      float o1 = a1 * cs[r].z + sgn * (p1 * cs[r].w);
      KB[(8 * w + r) * KSTR + lane] = packh((_Float16)o0, (_Float16)o1);
    }
    #pragma unroll
    for (int rp = 0; rp < 4; ++rp) {
      int kp = 4 * w + rp;
      VB[(2 * lane) * VSTR + kp]     = packh((_Float16)pva[rp].x, (_Float16)pvb[rp].x);
      VB[(2 * lane + 1) * VSTR + kp] = packh((_Float16)pva[rp].y, (_Float16)pvb[rp].y);
    }
  };

  #pragma unroll 1
  for (int sp = 0; sp < 2; ++sp) {
    const int qs = sp ? p : (3 - p);
    const int qrow = qs * 256 + w * 32 + l31;

    const float* qbase = Qg + (cbase + qrow) * 2048 + hoff;
    float xq[8][8];
    #pragma unroll
    for (int ds = 0; ds < 8; ++ds) {
      const float* ptr = qbase + ds * 16 + lg2 * 8;
      f32x4 v0 = ld_f32x4(ptr);
      f32x4 v1 = ld_f32x4(ptr + 4);
      xq[ds][0]=v0.x; xq[ds][1]=v0.y; xq[ds][2]=v0.z; xq[ds][3]=v0.w;
      xq[ds][4]=v1.x; xq[ds][5]=v1.y; xq[ds][6]=v1.z; xq[ds][7]=v1.w;
    }
    const float* trowq = tab + (size_t)(tb + qrow) * 128 + lg2 * 16;
    #pragma unroll
    for (int ds = 0; ds < 4; ++ds) {
      #pragma unroll
      for (int i2 = 0; i2 < 4; ++i2) {
        f32x4 cs = ld_f32x4(trowq + ds * 32 + i2 * 4);
        int i0 = 2 * i2;
        float a0 = xq[ds][i0],     b0 = xq[ds + 4][i0];
        xq[ds][i0]     = a0 * cs.x - b0 * cs.y;
        xq[ds + 4][i0] = b0 * cs.x + a0 * cs.y;
        float a1 = xq[ds][i0 + 1], b1 = xq[ds + 4][i0 + 1];
        xq[ds][i0 + 1]     = a1 * cs.z - b1 * cs.w;
        xq[ds + 4][i0 + 1] = b1 * cs.z + a1 * cs.w;
      }
    }
    f16x8 qh[8];
    #pragma unroll
    for (int ds = 0; ds < 8; ++ds)
      #pragma unroll
      for (int i = 0; i < 8; ++i)
        qh[ds][i] = (_Float16)(xq[ds][i] * QSCALE);

    f32x16 O[4];
    #pragma unroll
    for (int n = 0; n < 4; ++n) O[n] = (f32x16)0.0f;
    float m2 = -1e30f, lsum = 0.0f;
    const int  nt    = 4 * (qs + 1);
    const int  jmaxw = 4 * qs + (w >> 1);
    const bool oddw  = w & 1;

    issue(0);
    xform(0, 0);
    __syncthreads();

    for (int j = 0; j < nt; ++j) {
      const int s = j & 1;
      const bool more = (j + 1 < nt);
      if (more) issue(j + 1);

      if (j <= jmaxw) {
        const bool full = oddw || (j < jmaxw);
        const u32* KB = lds + s * STG;
        const u32* VB = KB + KBUF;
        const u32* kr0 = KB + (size_t)l31 * KSTR + lg2 * 4;
        const u32* kr1 = kr0 + (size_t)32 * KSTR;

        f32x16 S0 = (f32x16)0.0f, S1 = (f32x16)0.0f;
        __builtin_amdgcn_s_setprio(1);
        #pragma unroll
        for (int ds = 0; ds < 8; ++ds) {
          S0 = MFMA(ld_frag(kr0 + ds * 8), qh[ds], S0);
          if (full) S1 = MFMA(ld_frag(kr1 + ds * 8), qh[ds], S1);
        }
        __builtin_amdgcn_s_setprio(0);

        if (j == jmaxw) {
          #pragma unroll
          for (int r = 0; r < 16; ++r) {
            int crow = (r & 3) + 8 * (r >> 2) + 4 * lg2;
            if (crow > l31) { if (oddw) S1[r] = -1e30f; else S0[r] = -1e30f; }
          }
        }

        float tm = S0[0];
        #pragma unroll
        for (int r = 1; r < 16; ++r) tm = fmaxf(tm, S0[r]);
        if (full) {
          #pragma unroll
          for (int r = 0; r < 16; ++r) tm = fmaxf(tm, S1[r]);
        }
        tm = fmaxf(tm, __shfl_xor(tm, 32));
        if (!__all(tm <= m2 + 8.0f)) {
          float m2n = fmaxf(m2, tm);
          float fac = exp2f(m2 - m2n);
          lsum *= fac;
          #pragma unroll
          for (int r = 0; r < 16; ++r) {
            int rq = (r & 3) + 8 * (r >> 2) + 4 * lg2;
            float fr = __shfl(fac, rq);
            O[0][r] *= fr; O[1][r] *= fr; O[2][r] *= fr; O[3][r] *= fr;
          }
          m2 = m2n;
        }
        u32 U[16];
        float ps = 0.0f;
        #pragma unroll
        for (int t = 0; t < 8; ++t) {
          float e0 = exp2f(S0[2 * t]     - m2);
          float e1 = exp2f(S0[2 * t + 1] - m2);
          U[t] = packh((_Float16)e0, (_Float16)e1);
          ps += e0 + e1;
        }
        if (full) {
          #pragma unroll
          for (int t = 0; t < 8; ++t) {
            float e0 = exp2f(S1[2 * t]     - m2);
            float e1 = exp2f(S1[2 * t + 1] - m2);
            U[8 + t] = packh((_Float16)e0, (_Float16)e1);
            ps += e0 + e1;
          }
        }
        ps += __shfl_xor(ps, 32);
        lsum += ps;

        __builtin_amdgcn_s_setprio(1);
        #pragma unroll
        for (int ks = 0; ks < 4; ++ks) {
          if (ks >= 2 && !full) continue;
          u32 a0 = U[4 * ks + 0], a1 = U[4 * ks + 1];
          u32 b0 = U[4 * ks + 2], b1 = U[4 * ks + 3];
          asm("v_permlane32_swap_b32 %0, %1" : "+v"(a0), "+v"(b0));
          asm("v_permlane32_swap_b32 %0, %1" : "+v"(a1), "+v"(b1));
          u32x4 t4; t4.x = a0; t4.y = a1; t4.z = b0; t4.w = b1;
          f16x8 pa = __builtin_bit_cast(f16x8, t4);
          #pragma unroll
          for (int n = 0; n < 4; ++n) {
            const u32* vp = VB + (size_t)(32 * n + l31) * VSTR + 8 * ks + 4 * lg2;
            O[n] = MFMA(pa, ld_frag(vp), O[n]);
          }
        }
        __builtin_amdgcn_s_setprio(0);
      }

      if (more) xform(j + 1, s ^ 1);
      __syncthreads();
    }

    float inv = 1.0f / lsum;
    #pragma unroll
    for (int r = 0; r < 16; ++r) {
      int rq = (r & 3) + 8 * (r >> 2) + 4 * lg2;
      float fi = __shfl(inv, rq);
      float* orow = Og + (cbase + qs * 256 + w * 32 + rq) * 2048 + hoff + l31;
      orow[0]  = O[0][r] * fi;
      orow[32] = O[1][r] * fi;
      orow[64] = O[2][r] * fi;
      orow[96] = O[3][r] * fi;
    }
  }
}

extern "C" void kernel_launch(void* const* d_in, const int* in_sizes, int n_in,
                              void* d_out, int out_size, void* d_ws, size_t ws_size,
                              hipStream_t stream) {
  const float* q = (const float*)d_in[0];
  const float* k = (const float*)d_in[1];
  const float* v = (const float*)d_in[2];
  const int* start = (const int*)d_in[3];
  float* out = (float*)d_out;

  float* tab = (float*)d_ws;                          // 2 MB
  const size_t KH_OFFB = 2u * 1024 * 1024;            // 64 MB
  const size_t VT_OFFB = KH_OFFB + 64u * 1024 * 1024; // 64 MB
  const size_t NEED = VT_OFFB + 64u * 1024 * 1024;    // 130 MB total

  rope_table_k<<<dim3(1024), dim3(256), 0, stream>>>(start, tab);

  if (ws_size >= NEED) {
    u32* Kh = (u32*)((char*)d_ws + KH_OFFB);
    u32* VT = (u32*)((char*)d_ws + VT_OFFB);
    prep_k_kernel<<<dim3(65536), dim3(256), 0, stream>>>(k, tab, Kh);
    prep_vt_kernel<<<dim3(4096), dim3(256), 0, stream>>>(v, VT);
    attn_f16_k<<<dim3(512), dim3(512), 0, stream>>>(q, Kh, VT, out, tab);
  } else {
    chunked_attn_fb<<<dim3(512), dim3(512), 0, stream>>>(q, k, v, out, tab);
  }
}

// Round 11
// 287.037 us; speedup vs baseline: 1.2682x; 1.0221x over previous
//
#include <hip/hip_runtime.h>

// ChunkedSelfAttention (RoPE + per-chunk causal SDPA), MI355X gfx950.
// R11: R6 skeleton (known-pass) + conflict-free LDS placement: reg-staged
// chunks scattered into padded rows (K stride 66 dw, V stride 34 dw ->
// bank=(2*row+col)%32, 2-way max = free), b64 fragment reads (R4-proven).
// Micro: cvt_pkrtz for P pack (R7-proven), parallel fmax tree.
// Prep kernels + decode + math verbatim R6.

typedef __attribute__((ext_vector_type(2)))  float     f32x2;
typedef __attribute__((ext_vector_type(4)))  float     f32x4;
typedef __attribute__((ext_vector_type(16))) float     f32x16;
typedef __attribute__((ext_vector_type(8)))  _Float16  f16x8;
typedef unsigned int   u32;
typedef unsigned short u16;
typedef __attribute__((ext_vector_type(4))) unsigned int u32x4;

#define MFMA(a, b, c) __builtin_amdgcn_mfma_f32_32x32x16_f16(a, b, c, 0, 0, 0)

constexpr int Ll = 4096;
constexpr float QSCALE = 0.08838834764831845f * 1.4426950408889634f; // 1/sqrt(128)*log2(e)

// padded LDS (dwords): K [64][66], V^T [128][34]; stage = 8576 dw, dbuf.
#define KSTR 66
#define VSTR 34
#define KBUF (64 * KSTR)
#define STG  (KBUF + 128 * VSTR)   // 8576 dw = 34304 B

__device__ __forceinline__ f32x4 ld_f32x4(const void* p) { f32x4 v; __builtin_memcpy(&v, p, 16); return v; }
__device__ __forceinline__ f32x2 ld_f32x2(const void* p) { f32x2 v; __builtin_memcpy(&v, p, 8);  return v; }
__device__ __forceinline__ u32x4 ld_u32x4(const void* p) { u32x4 v; __builtin_memcpy(&v, p, 16); return v; }
__device__ __forceinline__ void  st_u32x4(void* p, u32x4 v) { __builtin_memcpy(p, &v, 16); }
// 8B-granular frag ops (padded rows are 8B- but not 16B-aligned)
__device__ __forceinline__ f16x8 ld_frag(const u32* dwp) {
  f16x8 v;
  __builtin_memcpy(&v, dwp, 8);
  __builtin_memcpy(((char*)&v) + 8, dwp + 2, 8);
  return v;
}
__device__ __forceinline__ void st_frag(u32* dwp, u32x4 v) {
  __builtin_memcpy(dwp, &v, 8);
  __builtin_memcpy(dwp + 2, ((char*)&v) + 8, 8);
}
__device__ __forceinline__ u32 packh(_Float16 a, _Float16 b) {
  return (u32)__builtin_bit_cast(u16, a) | ((u32)__builtin_bit_cast(u16, b) << 16);
}
__device__ __forceinline__ u32 pkrtz(float a, float b) {
  auto v = __builtin_amdgcn_cvt_pkrtz(a, b);
  u32 r; __builtin_memcpy(&r, &v, 4); return r;
}

// ---- cos/sin table (verbatim R6) ----
__global__ void rope_table_k(const int* __restrict__ startp, float* __restrict__ tab) {
  int idx = blockIdx.x * 256 + threadIdx.x;
  int t = idx >> 6, hid = idx & 63;
  float a = (float)hid * (-0.14391156831212878f);
  float invf = expf(a);
  float ang = (float)(t + startp[0]) * invf;
  tab[2 * idx]     = cosf(ang);
  tab[2 * idx + 1] = sinf(ang);
}

// ---- prepass K (verbatim R6) ----
__global__ __launch_bounds__(256)
void prep_k_kernel(const float* __restrict__ Kg, const float* __restrict__ tab,
                   u32* __restrict__ Kh) {
  const int R    = blockIdx.x * 4 + (threadIdx.x >> 6);
  const int lane = threadIdx.x & 63;
  const int h  = R & 15;
  const int bt = R >> 4;
  const int b  = bt >> 12;
  const int t  = bt & 4095;
  const int c  = t >> 10;
  const int j  = (t >> 6) & 15;
  const int row = t & 63;
  const int GID = (b * 4 + c) * 16 + h;
  const int sw  = (row & 7) << 4;
  const int dc  = ((4 * lane) ^ sw) >> 1;
  f32x2 a = ld_f32x2(Kg + (size_t)R * 128 + dc);
  float p0 = __shfl_xor(a.x, 32);
  float p1 = __shfl_xor(a.y, 32);
  f32x4 cs = ld_f32x4(tab + (size_t)t * 128 + 2 * (dc & 63));
  const float sgn = (dc < 64) ? -1.0f : 1.0f;
  float o0 = a.x * cs.x + sgn * (p0 * cs.y);
  float o1 = a.y * cs.z + sgn * (p1 * cs.w);
  Kh[((size_t)(GID * 16 + j) * 64 + row) * 64 + lane] = packh((_Float16)o0, (_Float16)o1);
}

// ---- prepass V^T (verbatim R6) ----
__global__ __launch_bounds__(256)
void prep_vt_kernel(const float* __restrict__ Vg, u32* __restrict__ VT) {
  __shared__ __align__(16) u32 tile[4096];
  const int gj  = blockIdx.x;
  const int GID = gj >> 4, j = gj & 15;
  const int h = GID & 15, c = (GID >> 4) & 3, b = GID >> 6;
  const int tid = threadIdx.x;
  const size_t rowbase = ((size_t)(b * 4096 + c * 1024 + j * 64)) * 16 + h;
  const int k  = tid >> 2;
  const int dq = tid & 3;
  u16* t16 = (u16*)tile;
  #pragma unroll
  for (int it = 0; it < 8; ++it) {
    int dv0 = dq * 4 + 16 * it;
    f32x4 v4 = ld_f32x4(Vg + (rowbase + (size_t)k * 16) * 128 + dv0);
    #pragma unroll
    for (int u = 0; u < 4; ++u) {
      int dv = dv0 + u;
      int ci = k ^ ((dv & 7) << 3);
      t16[dv * 64 + ci] = __builtin_bit_cast(u16, (_Float16)v4[u]);
    }
  }
  __syncthreads();
  const u32* tsrc = tile + 16 * tid;
  u32* dst = VT + (size_t)gj * 4096 + 16 * tid;
  #pragma unroll
  for (int u = 0; u < 4; ++u) st_u32x4(dst + 4 * u, ld_u32x4(tsrc + 4 * u));
}

// ================= main attention (R6 skeleton, padded LDS) =================
__global__ __launch_bounds__(512, 2)
void attn_f16_k(const float* __restrict__ Qg, const u32* __restrict__ Kh,
                const u32* __restrict__ VT, float* __restrict__ Og,
                const float* __restrict__ tab) {
  __shared__ __align__(16) u32 lds[2 * STG];   // 68608 B, double-buffered

  const int bx  = blockIdx.x;            // R6 decode (known-pass)
  const int h   = bx & 15;
  const int p   = (bx >> 4) & 1;
  const int c   = (bx >> 5) & 3;
  const int b   = bx >> 7;
  const int tid = threadIdx.x;
  const int w   = tid >> 6;
  const int lane= tid & 63;
  const int l31 = lane & 31;
  const int lg2 = lane >> 5;

  const size_t cbase = (size_t)(b * Ll + c * 1024);
  const size_t hoff  = (size_t)h * 128;
  const int tb  = c * 1024;
  const int GID = (b * 4 + c) * 16 + h;
  const u32* khg = Kh + (size_t)GID * 16 * 4096;
  const u32* vtg = VT + (size_t)GID * 16 * 4096;

  u32x4 stg[4];
  auto issue = [&](int j) {
    #pragma unroll
    for (int i = 0; i < 4; ++i) {
      int ch = w + 8 * i;                // 32 chunks of 1 KB: 0..15 K, 16..31 VT
      const u32* src = (ch < 16) ? (khg + (size_t)j * 4096 + ch * 256 + 4 * lane)
                                 : (vtg + (size_t)j * 4096 + (ch - 16) * 256 + 4 * lane);
      stg[i] = ld_u32x4(src);
    }
  };
  // scatter chunks into padded rows: identical content, conflict-free banks
  auto store_stage = [&](int s) {
    u32* dst0 = lds + (size_t)s * STG;
    #pragma unroll
    for (int i = 0; i < 4; ++i) {
      int ch = w + 8 * i;
      u32* dst;
      if (ch < 16) {                       // K: 1KB chunk = 4 rows x 16 chunks
        int row = 4 * ch + (lane >> 4);
        dst = dst0 + row * KSTR + 4 * (lane & 15);
      } else {                             // V: 1KB chunk = 8 rows x 8 chunks
        int row = 8 * (ch - 16) + (lane >> 3);
        dst = dst0 + KBUF + row * VSTR + 4 * (lane & 7);
      }
      st_frag(dst, stg[i]);
    }
  };

  auto vmax16 = [](const f32x16& S) {
    float a0 = fmaxf(S[0], S[1]),   a1 = fmaxf(S[2], S[3]);
    float a2 = fmaxf(S[4], S[5]),   a3 = fmaxf(S[6], S[7]);
    float a4 = fmaxf(S[8], S[9]),   a5 = fmaxf(S[10], S[11]);
    float a6 = fmaxf(S[12], S[13]), a7 = fmaxf(S[14], S[15]);
    float b0 = fmaxf(a0, a1), b1 = fmaxf(a2, a3);
    float b2 = fmaxf(a4, a5), b3 = fmaxf(a6, a7);
    return fmaxf(fmaxf(b0, b1), fmaxf(b2, b3));
  };

  #pragma unroll 1
  for (int sp = 0; sp < 2; ++sp) {
    const int qs = sp ? p : (3 - p);            // heavy strip first
    const int qrow = qs * 256 + w * 32 + l31;

    // ---------- Q prologue: load f32, rope, scale, f16 (verbatim R6) ----------
    const float* qbase = Qg + (cbase + qrow) * 2048 + hoff;
    float xq[8][8];
    #pragma unroll
    for (int ds = 0; ds < 8; ++ds) {
      const float* ptr = qbase + ds * 16 + lg2 * 8;
      f32x4 v0 = ld_f32x4(ptr);
      f32x4 v1 = ld_f32x4(ptr + 4);
      xq[ds][0]=v0.x; xq[ds][1]=v0.y; xq[ds][2]=v0.z; xq[ds][3]=v0.w;
      xq[ds][4]=v1.x; xq[ds][5]=v1.y; xq[ds][6]=v1.z; xq[ds][7]=v1.w;
    }
    const float* trowq = tab + (size_t)(tb + qrow) * 128 + lg2 * 16;
    #pragma unroll
    for (int ds = 0; ds < 4; ++ds) {
      #pragma unroll
      for (int i2 = 0; i2 < 4; ++i2) {
        f32x4 cs = ld_f32x4(trowq + ds * 32 + i2 * 4);
        int i0 = 2 * i2;
        float a0 = xq[ds][i0],     b0 = xq[ds + 4][i0];
        xq[ds][i0]     = a0 * cs.x - b0 * cs.y;
        xq[ds + 4][i0] = b0 * cs.x + a0 * cs.y;
        float a1 = xq[ds][i0 + 1], b1 = xq[ds + 4][i0 + 1];
        xq[ds][i0 + 1]     = a1 * cs.z - b1 * cs.w;
        xq[ds + 4][i0 + 1] = b1 * cs.z + a1 * cs.w;
      }
    }
    f16x8 qh[8];
    #pragma unroll
    for (int ds = 0; ds < 8; ++ds)
      #pragma unroll
      for (int i = 0; i < 8; ++i)
        qh[ds][i] = (_Float16)(xq[ds][i] * QSCALE);

    // ---------- state ----------
    f32x16 O[4];
    #pragma unroll
    for (int n = 0; n < 4; ++n) O[n] = (f32x16)0.0f;
    float m2 = -1e30f, lsum = 0.0f;
    const int  nt    = 4 * (qs + 1);
    const int  jmaxw = 4 * qs + (w >> 1);
    const bool oddw  = w & 1;

    issue(0);
    store_stage(0);
    __syncthreads();

    for (int j = 0; j < nt; ++j) {
      const int s = j & 1;
      const bool more = (j + 1 < nt);
      if (more) issue(j + 1);          // global loads fly under compute

      if (j <= jmaxw) {
        const bool full = oddw || (j < jmaxw);
        const u32* KB = lds + (size_t)s * STG;
        const u32* VB = KB + KBUF;
        const u32* kr0 = KB + (size_t)l31 * KSTR;
        const u32* kr1 = kr0 + 32 * KSTR;
        const int  swk = (l31 & 7) << 2;      // dword-col XOR (baked in global)

        // ---- QK^T (swapped): S^T[k][q] = K . Q^T ----
        f32x16 S0 = (f32x16)0.0f, S1 = (f32x16)0.0f;
        __builtin_amdgcn_s_setprio(1);
        #pragma unroll
        for (int ds = 0; ds < 8; ++ds) {
          int dc = (8 * ds + 4 * lg2) ^ swk;
          S0 = MFMA(ld_frag(kr0 + dc), qh[ds], S0);
          if (full) S1 = MFMA(ld_frag(kr1 + dc), qh[ds], S1);
        }
        __builtin_amdgcn_s_setprio(0);

        // ---- causal mask (diagonal tile only) ----
        if (j == jmaxw) {
          #pragma unroll
          for (int r = 0; r < 16; ++r) {
            int crow = (r & 3) + 8 * (r >> 2) + 4 * lg2;
            if (crow > l31) { if (oddw) S1[r] = -1e30f; else S0[r] = -1e30f; }
          }
        }

        // ---- online softmax (base-2), T13 deferred rescale ----
        float tm = vmax16(S0);
        if (full) tm = fmaxf(tm, vmax16(S1));
        tm = fmaxf(tm, __shfl_xor(tm, 32));
        if (!__all(tm <= m2 + 8.0f)) {
          float m2n = fmaxf(m2, tm);
          float fac = exp2f(m2 - m2n);
          lsum *= fac;
          #pragma unroll
          for (int r = 0; r < 16; ++r) {
            int rq = (r & 3) + 8 * (r >> 2) + 4 * lg2;
            float fr = __shfl(fac, rq);
            O[0][r] *= fr; O[1][r] *= fr; O[2][r] *= fr; O[3][r] *= fr;
          }
          m2 = m2n;
        }
        u32 U[16];
        float ps = 0.0f;
        #pragma unroll
        for (int t = 0; t < 8; ++t) {
          float e0 = exp2f(S0[2 * t]     - m2);
          float e1 = exp2f(S0[2 * t + 1] - m2);
          U[t] = pkrtz(e0, e1);
          ps += e0 + e1;
        }
        if (full) {
          #pragma unroll
          for (int t = 0; t < 8; ++t) {
            float e0 = exp2f(S1[2 * t]     - m2);
            float e1 = exp2f(S1[2 * t + 1] - m2);
            U[8 + t] = pkrtz(e0, e1);
            ps += e0 + e1;
          }
        }
        ps += __shfl_xor(ps, 32);
        lsum += ps;

        // ---- PV: P fragments in-register via permlane32_swap ----
        __builtin_amdgcn_s_setprio(1);
        #pragma unroll
        for (int ks = 0; ks < 4; ++ks) {
          if (ks >= 2 && !full) continue;
          u32 a0 = U[4 * ks + 0], a1 = U[4 * ks + 1];
          u32 b0 = U[4 * ks + 2], b1 = U[4 * ks + 3];
          asm("v_permlane32_swap_b32 %0, %1" : "+v"(a0), "+v"(b0));
          asm("v_permlane32_swap_b32 %0, %1" : "+v"(a1), "+v"(b1));
          u32x4 t4; t4.x = a0; t4.y = a1; t4.z = b0; t4.w = b1;
          f16x8 pa = __builtin_bit_cast(f16x8, t4);
          int dcv = (8 * ks + 4 * lg2) ^ swk;
          #pragma unroll
          for (int n = 0; n < 4; ++n) {
            O[n] = MFMA(pa, ld_frag(VB + (size_t)(32 * n + l31) * VSTR + dcv), O[n]);
          }
        }
        __builtin_amdgcn_s_setprio(0);
      }

      if (more) store_stage(s ^ 1);
      __syncthreads();
    }

    // ---------- epilogue ----------
    float inv = 1.0f / lsum;
    #pragma unroll
    for (int r = 0; r < 16; ++r) {
      int rq = (r & 3) + 8 * (r >> 2) + 4 * lg2;
      float fi = __shfl(inv, rq);
      float* orow = Og + (cbase + qs * 256 + w * 32 + rq) * 2048 + hoff + l31;
      orow[0]  = O[0][r] * fi;
      orow[32] = O[1][r] * fi;
      orow[64] = O[2][r] * fi;
      orow[96] = O[3][r] * fi;
    }
  }
}

// ================= fallback (R4/R6, passed) =================
__global__ __launch_bounds__(512, 2)
void chunked_attn_fb(const float* __restrict__ Qg, const float* __restrict__ Kg,
                     const float* __restrict__ Vg, float* __restrict__ Og,
                     const float* __restrict__ tab) {
  __shared__ __align__(16) u32 lds[2 * STG];

  const int bx  = blockIdx.x;
  const int h   = bx & 15;
  const int p   = (bx >> 4) & 1;
  const int c   = (bx >> 5) & 3;
  const int b   = bx >> 7;
  const int tid = threadIdx.x;
  const int w   = tid >> 6;
  const int lane= tid & 63;
  const int l31 = lane & 31;
  const int lg2 = lane >> 5;

  const size_t cbase = (size_t)(b * Ll + c * 1024);
  const size_t hoff  = (size_t)h * 128;
  const int tb = c * 1024;

  f32x2 pk[8], pva[4], pvb[4];

  auto issue = [&](int j) {
    const float* kb_ = Kg + (cbase + (size_t)j * 64) * 2048 + hoff;
    const float* vb_ = Vg + (cbase + (size_t)j * 64) * 2048 + hoff;
    #pragma unroll
    for (int r = 0; r < 8; ++r)
      pk[r] = ld_f32x2(kb_ + (size_t)(8 * w + r) * 2048 + 2 * lane);
    #pragma unroll
    for (int rp = 0; rp < 4; ++rp) {
      const float* vr = vb_ + (size_t)(8 * w + 2 * rp) * 2048 + 2 * lane;
      pva[rp] = ld_f32x2(vr);
      pvb[rp] = ld_f32x2(vr + 2048);
    }
  };

  auto xform = [&](int j, int s) {
    u32* KB = lds + s * STG;
    u32* VB = KB + KBUF;
    const float* tbase = tab + (size_t)(tb + j * 64) * 128 + 4 * l31;
    f32x4 cs[8];
    #pragma unroll
    for (int r = 0; r < 8; ++r)
      cs[r] = ld_f32x4(tbase + (size_t)(8 * w + r) * 128);
    const float sgn = (lane < 32) ? -1.0f : 1.0f;
    #pragma unroll
    for (int r = 0; r < 8; ++r) {
      float a0 = pk[r].x, a1 = pk[r].y;
      float p0 = __shfl_xor(a0, 32), p1 = __shfl_xor(a1, 32);
      float o0 = a0 * cs[r].x + sgn * (p0 * cs[r].y);
      float o1 = a1 * cs[r].z + sgn * (p1 * cs[r].w);
      KB[(8 * w + r) * KSTR + lane] = packh((_Float16)o0, (_Float16)o1);
    }
    #pragma unroll
    for (int rp = 0; rp < 4; ++rp) {
      int kp = 4 * w + rp;
      VB[(2 * lane) * VSTR + kp]     = packh((_Float16)pva[rp].x, (_Float16)pvb[rp].x);
      VB[(2 * lane + 1) * VSTR + kp] = packh((_Float16)pva[rp].y, (_Float16)pvb[rp].y);
    }
  };

  #pragma unroll 1
  for (int sp = 0; sp < 2; ++sp) {
    const int qs = sp ? p : (3 - p);
    const int qrow = qs * 256 + w * 32 + l31;

    const float* qbase = Qg + (cbase + qrow) * 2048 + hoff;
    float xq[8][8];
    #pragma unroll
    for (int ds = 0; ds < 8; ++ds) {
      const float* ptr = qbase + ds * 16 + lg2 * 8;
      f32x4 v0 = ld_f32x4(ptr);
      f32x4 v1 = ld_f32x4(ptr + 4);
      xq[ds][0]=v0.x; xq[ds][1]=v0.y; xq[ds][2]=v0.z; xq[ds][3]=v0.w;
      xq[ds][4]=v1.x; xq[ds][5]=v1.y; xq[ds][6]=v1.z; xq[ds][7]=v1.w;
    }
    const float* trowq = tab + (size_t)(tb + qrow) * 128 + lg2 * 16;
    #pragma unroll
    for (int ds = 0; ds < 4; ++ds) {
      #pragma unroll
      for (int i2 = 0; i2 < 4; ++i2) {
        f32x4 cs = ld_f32x4(trowq + ds * 32 + i2 * 4);
        int i0 = 2 * i2;
        float a0 = xq[ds][i0],     b0 = xq[ds + 4][i0];
        xq[ds][i0]     = a0 * cs.x - b0 * cs.y;
        xq[ds + 4][i0] = b0 * cs.x + a0 * cs.y;
        float a1 = xq[ds][i0 + 1], b1 = xq[ds + 4][i0 + 1];
        xq[ds][i0 + 1]     = a1 * cs.z - b1 * cs.w;
        xq[ds + 4][i0 + 1] = b1 * cs.z + a1 * cs.w;
      }
    }
    f16x8 qh[8];
    #pragma unroll
    for (int ds = 0; ds < 8; ++ds)
      #pragma unroll
      for (int i = 0; i < 8; ++i)
        qh[ds][i] = (_Float16)(xq[ds][i] * QSCALE);

    f32x16 O[4];
    #pragma unroll
    for (int n = 0; n < 4; ++n) O[n] = (f32x16)0.0f;
    float m2 = -1e30f, lsum = 0.0f;
    const int  nt    = 4 * (qs + 1);
    const int  jmaxw = 4 * qs + (w >> 1);
    const bool oddw  = w & 1;

    issue(0);
    xform(0, 0);
    __syncthreads();

    for (int j = 0; j < nt; ++j) {
      const int s = j & 1;
      const bool more = (j + 1 < nt);
      if (more) issue(j + 1);

      if (j <= jmaxw) {
        const bool full = oddw || (j < jmaxw);
        const u32* KB = lds + s * STG;
        const u32* VB = KB + KBUF;
        const u32* kr0 = KB + (size_t)l31 * KSTR + lg2 * 4;
        const u32* kr1 = kr0 + (size_t)32 * KSTR;

        f32x16 S0 = (f32x16)0.0f, S1 = (f32x16)0.0f;
        __builtin_amdgcn_s_setprio(1);
        #pragma unroll
        for (int ds = 0; ds < 8; ++ds) {
          S0 = MFMA(ld_frag(kr0 + ds * 8), qh[ds], S0);
          if (full) S1 = MFMA(ld_frag(kr1 + ds * 8), qh[ds], S1);
        }
        __builtin_amdgcn_s_setprio(0);

        if (j == jmaxw) {
          #pragma unroll
          for (int r = 0; r < 16; ++r) {
            int crow = (r & 3) + 8 * (r >> 2) + 4 * lg2;
            if (crow > l31) { if (oddw) S1[r] = -1e30f; else S0[r] = -1e30f; }
          }
        }

        float tm = S0[0];
        #pragma unroll
        for (int r = 1; r < 16; ++r) tm = fmaxf(tm, S0[r]);
        if (full) {
          #pragma unroll
          for (int r = 0; r < 16; ++r) tm = fmaxf(tm, S1[r]);
        }
        tm = fmaxf(tm, __shfl_xor(tm, 32));
        if (!__all(tm <= m2 + 8.0f)) {
          float m2n = fmaxf(m2, tm);
          float fac = exp2f(m2 - m2n);
          lsum *= fac;
          #pragma unroll
          for (int r = 0; r < 16; ++r) {
            int rq = (r & 3) + 8 * (r >> 2) + 4 * lg2;
            float fr = __shfl(fac, rq);
            O[0][r] *= fr; O[1][r] *= fr; O[2][r] *= fr; O[3][r] *= fr;
          }
          m2 = m2n;
        }
        u32 U[16];
        float ps = 0.0f;
        #pragma unroll
        for (int t = 0; t < 8; ++t) {
          float e0 = exp2f(S0[2 * t]     - m2);
          float e1 = exp2f(S0[2 * t + 1] - m2);
          U[t] = packh((_Float16)e0, (_Float16)e1);
          ps += e0 + e1;
        }
        if (full) {
          #pragma unroll
          for (int t = 0; t < 8; ++t) {
            float e0 = exp2f(S1[2 * t]     - m2);
            float e1 = exp2f(S1[2 * t + 1] - m2);
            U[8 + t] = packh((_Float16)e0, (_Float16)e1);
            ps += e0 + e1;
          }
        }
        ps += __shfl_xor(ps, 32);
        lsum += ps;

        __builtin_amdgcn_s_setprio(1);
        #pragma unroll
        for (int ks = 0; ks < 4; ++ks) {
          if (ks >= 2 && !full) continue;
          u32 a0 = U[4 * ks + 0], a1 = U[4 * ks + 1];
          u32 b0 = U[4 * ks + 2], b1 = U[4 * ks + 3];
          asm("v_permlane32_swap_b32 %0, %1" : "+v"(a0), "+v"(b0));
          asm("v_permlane32_swap_b32 %0, %1" : "+v"(a1), "+v"(b1));
          u32x4 t4; t4.x = a0; t4.y = a1; t4.z = b0; t4.w = b1;
          f16x8 pa = __builtin_bit_cast(f16x8, t4);
          #pragma unroll
          for (int n = 0; n < 4; ++n) {
            const u32* vp = VB + (size_t)(32 * n + l31) * VSTR + 8 * ks + 4 * lg2;
            O[n] = MFMA(pa, ld_frag(vp), O[n]);
          }
        }
        __builtin_amdgcn_s_setprio(0);
      }

      if (more) xform(j + 1, s ^ 1);
      __syncthreads();
    }

    float inv = 1.0f / lsum;
    #pragma unroll
    for (int r = 0; r < 16; ++r) {
      int rq = (r & 3) + 8 * (r >> 2) + 4 * lg2;
      float fi = __shfl(inv, rq);
      float* orow = Og + (cbase + qs * 256 + w * 32 + rq) * 2048 + hoff + l31;
      orow[0]  = O[0][r] * fi;
      orow[32] = O[1][r] * fi;
      orow[64] = O[2][r] * fi;
      orow[96] = O[3][r] * fi;
    }
  }
}

extern "C" void kernel_launch(void* const* d_in, const int* in_sizes, int n_in,
                              void* d_out, int out_size, void* d_ws, size_t ws_size,
                              hipStream_t stream) {
  const float* q = (const float*)d_in[0];
  const float* k = (const float*)d_in[1];
  const float* v = (const float*)d_in[2];
  const int* start = (const int*)d_in[3];
  float* out = (float*)d_out;

  float* tab = (float*)d_ws;                          // 2 MB
  const size_t KH_OFFB = 2u * 1024 * 1024;            // 64 MB
  const size_t VT_OFFB = KH_OFFB + 64u * 1024 * 1024; // 64 MB
  const size_t NEED = VT_OFFB + 64u * 1024 * 1024;    // 130 MB total

  rope_table_k<<<dim3(1024), dim3(256), 0, stream>>>(start, tab);

  if (ws_size >= NEED) {
    u32* Kh = (u32*)((char*)d_ws + KH_OFFB);
    u32* VT = (u32*)((char*)d_ws + VT_OFFB);
    prep_k_kernel<<<dim3(65536), dim3(256), 0, stream>>>(k, tab, Kh);
    prep_vt_kernel<<<dim3(4096), dim3(256), 0, stream>>>(v, VT);
    attn_f16_k<<<dim3(512), dim3(512), 0, stream>>>(q, Kh, VT, out, tab);
  } else {
    chunked_attn_fb<<<dim3(512), dim3(512), 0, stream>>>(q, k, v, out, tab);
  }
}

// Round 12
// 270.120 us; speedup vs baseline: 1.3476x; 1.0626x over previous
//
#include <hip/hip_runtime.h>

// ChunkedSelfAttention (RoPE + per-chunk causal SDPA), MI355X gfx950.
// R12: R6 attn kernel VERBATIM (best-known: 190us attn). Only change:
// prep_k + prep_vt merged into ONE launch (bodies verbatim, blockIdx-range
// dispatch) to remove a kernel boundary and overlap K-prep tail with
// V-prep. rope table + fallback unchanged.

typedef __attribute__((ext_vector_type(2)))  float     f32x2;
typedef __attribute__((ext_vector_type(4)))  float     f32x4;
typedef __attribute__((ext_vector_type(16))) float     f32x16;
typedef __attribute__((ext_vector_type(8)))  _Float16  f16x8;
typedef unsigned int   u32;
typedef unsigned short u16;
typedef __attribute__((ext_vector_type(4))) unsigned int u32x4;

#define MFMA(a, b, c) __builtin_amdgcn_mfma_f32_32x32x16_f16(a, b, c, 0, 0, 0)

constexpr int Ll = 4096;
constexpr float QSCALE = 0.08838834764831845f * 1.4426950408889634f; // 1/sqrt(128)*log2(e)

__device__ __forceinline__ f32x4 ld_f32x4(const void* p) { f32x4 v; __builtin_memcpy(&v, p, 16); return v; }
__device__ __forceinline__ f32x2 ld_f32x2(const void* p) { f32x2 v; __builtin_memcpy(&v, p, 8);  return v; }
__device__ __forceinline__ u32x4 ld_u32x4(const void* p) { u32x4 v; __builtin_memcpy(&v, p, 16); return v; }
__device__ __forceinline__ void  st_u32x4(void* p, u32x4 v) { __builtin_memcpy(p, &v, 16); }
__device__ __forceinline__ f16x8 ld_f16x8(const void* p) { f16x8 v; __builtin_memcpy(&v, p, 16); return v; }
__device__ __forceinline__ f16x8 ld_frag(const u32* dwp) {
  f16x8 v;
  __builtin_memcpy(&v, dwp, 8);
  __builtin_memcpy(((char*)&v) + 8, dwp + 2, 8);
  return v;
}
__device__ __forceinline__ u32 packh(_Float16 a, _Float16 b) {
  return (u32)__builtin_bit_cast(u16, a) | ((u32)__builtin_bit_cast(u16, b) << 16);
}

// ---- cos/sin table (verbatim R6) ----
__global__ void rope_table_k(const int* __restrict__ startp, float* __restrict__ tab) {
  int idx = blockIdx.x * 256 + threadIdx.x;
  int t = idx >> 6, hid = idx & 63;
  float a = (float)hid * (-0.14391156831212878f);
  float invf = expf(a);
  float ang = (float)(t + startp[0]) * invf;
  tab[2 * idx]     = cosf(ang);
  tab[2 * idx + 1] = sinf(ang);
}

// ---- merged prepass: blocks [0,65536) run the R6 prep_k body verbatim;
//      blocks [65536,69632) run the R6 prep_vt body verbatim. ----
__global__ __launch_bounds__(256)
void prep_merged_kernel(const float* __restrict__ Kg, const float* __restrict__ Vg,
                        const float* __restrict__ tab, u32* __restrict__ Kh,
                        u32* __restrict__ VT) {
  __shared__ __align__(16) u32 tile[4096];
  const int bx = blockIdx.x;
  if (bx < 65536) {
    // ======== R6 prep_k body (verbatim) ========
    const int R    = bx * 4 + (threadIdx.x >> 6);
    const int lane = threadIdx.x & 63;
    const int h  = R & 15;
    const int bt = R >> 4;
    const int b  = bt >> 12;
    const int t  = bt & 4095;
    const int c  = t >> 10;
    const int j  = (t >> 6) & 15;
    const int row = t & 63;
    const int GID = (b * 4 + c) * 16 + h;
    const int sw  = (row & 7) << 4;
    const int dc  = ((4 * lane) ^ sw) >> 1;
    f32x2 a = ld_f32x2(Kg + (size_t)R * 128 + dc);
    float p0 = __shfl_xor(a.x, 32);
    float p1 = __shfl_xor(a.y, 32);
    f32x4 cs = ld_f32x4(tab + (size_t)t * 128 + 2 * (dc & 63));
    const float sgn = (dc < 64) ? -1.0f : 1.0f;
    float o0 = a.x * cs.x + sgn * (p0 * cs.y);
    float o1 = a.y * cs.z + sgn * (p1 * cs.w);
    Kh[((size_t)(GID * 16 + j) * 64 + row) * 64 + lane] = packh((_Float16)o0, (_Float16)o1);
  } else {
    // ======== R6 prep_vt body (verbatim) ========
    const int gj  = bx - 65536;
    const int GID = gj >> 4, j = gj & 15;
    const int h = GID & 15, c = (GID >> 4) & 3, b = GID >> 6;
    const int tid = threadIdx.x;
    const size_t rowbase = ((size_t)(b * 4096 + c * 1024 + j * 64)) * 16 + h;
    const int k  = tid >> 2;
    const int dq = tid & 3;
    u16* t16 = (u16*)tile;
    #pragma unroll
    for (int it = 0; it < 8; ++it) {
      int dv0 = dq * 4 + 16 * it;
      f32x4 v4 = ld_f32x4(Vg + (rowbase + (size_t)k * 16) * 128 + dv0);
      #pragma unroll
      for (int u = 0; u < 4; ++u) {
        int dv = dv0 + u;
        int ci = k ^ ((dv & 7) << 3);
        t16[dv * 64 + ci] = __builtin_bit_cast(u16, (_Float16)v4[u]);
      }
    }
    __syncthreads();
    const u32* tsrc = tile + 16 * tid;
    u32* dst = VT + (size_t)gj * 4096 + 16 * tid;
    #pragma unroll
    for (int u = 0; u < 4; ++u) st_u32x4(dst + 4 * u, ld_u32x4(tsrc + 4 * u));
  }
}

// ================= main attention (R6 verbatim) =================
__global__ __launch_bounds__(512, 2)
void attn_f16_k(const float* __restrict__ Qg, const u32* __restrict__ Kh,
                const u32* __restrict__ VT, float* __restrict__ Og,
                const float* __restrict__ tab) {
  __shared__ __align__(16) u32 lds[2 * 8192];   // 64 KB, double-buffered

  const int bx  = blockIdx.x;
  const int h   = bx & 15;
  const int p   = (bx >> 4) & 1;
  const int c   = (bx >> 5) & 3;
  const int b   = bx >> 7;
  const int tid = threadIdx.x;
  const int w   = tid >> 6;
  const int lane= tid & 63;
  const int l31 = lane & 31;
  const int lg2 = lane >> 5;

  const size_t cbase = (size_t)(b * Ll + c * 1024);
  const size_t hoff  = (size_t)h * 128;
  const int tb  = c * 1024;
  const int GID = (b * 4 + c) * 16 + h;
  const u32* khg = Kh + (size_t)GID * 16 * 4096;
  const u32* vtg = VT + (size_t)GID * 16 * 4096;

  u32x4 stg[4];
  auto issue = [&](int j) {
    #pragma unroll
    for (int i = 0; i < 4; ++i) {
      int ch = w + 8 * i;                // 32 chunks of 1 KB: 0..15 K, 16..31 VT
      const u32* src = (ch < 16) ? (khg + (size_t)j * 4096 + ch * 256 + 4 * lane)
                                 : (vtg + (size_t)j * 4096 + (ch - 16) * 256 + 4 * lane);
      stg[i] = ld_u32x4(src);
    }
  };
  auto store_stage = [&](int s) {
    u32* dst0 = lds + (size_t)s * 8192;
    #pragma unroll
    for (int i = 0; i < 4; ++i) {
      int ch = w + 8 * i;
      st_u32x4(dst0 + ch * 256 + 4 * lane, stg[i]);
    }
  };

  #pragma unroll 1
  for (int sp = 0; sp < 2; ++sp) {
    const int qs = sp ? p : (3 - p);            // heavy strip first
    const int qrow = qs * 256 + w * 32 + l31;

    // ---------- Q prologue: load f32, rope, scale, f16 ----------
    const float* qbase = Qg + (cbase + qrow) * 2048 + hoff;
    float xq[8][8];
    #pragma unroll
    for (int ds = 0; ds < 8; ++ds) {
      const float* ptr = qbase + ds * 16 + lg2 * 8;
      f32x4 v0 = ld_f32x4(ptr);
      f32x4 v1 = ld_f32x4(ptr + 4);
      xq[ds][0]=v0.x; xq[ds][1]=v0.y; xq[ds][2]=v0.z; xq[ds][3]=v0.w;
      xq[ds][4]=v1.x; xq[ds][5]=v1.y; xq[ds][6]=v1.z; xq[ds][7]=v1.w;
    }
    const float* trowq = tab + (size_t)(tb + qrow) * 128 + lg2 * 16;
    #pragma unroll
    for (int ds = 0; ds < 4; ++ds) {
      #pragma unroll
      for (int i2 = 0; i2 < 4; ++i2) {
        f32x4 cs = ld_f32x4(trowq + ds * 32 + i2 * 4);
        int i0 = 2 * i2;
        float a0 = xq[ds][i0],     b0 = xq[ds + 4][i0];
        xq[ds][i0]     = a0 * cs.x - b0 * cs.y;
        xq[ds + 4][i0] = b0 * cs.x + a0 * cs.y;
        float a1 = xq[ds][i0 + 1], b1 = xq[ds + 4][i0 + 1];
        xq[ds][i0 + 1]     = a1 * cs.z - b1 * cs.w;
        xq[ds + 4][i0 + 1] = b1 * cs.z + a1 * cs.w;
      }
    }
    f16x8 qh[8];
    #pragma unroll
    for (int ds = 0; ds < 8; ++ds)
      #pragma unroll
      for (int i = 0; i < 8; ++i)
        qh[ds][i] = (_Float16)(xq[ds][i] * QSCALE);

    // ---------- state ----------
    f32x16 O[4];
    #pragma unroll
    for (int n = 0; n < 4; ++n) O[n] = (f32x16)0.0f;
    float m2 = -1e30f, lsum = 0.0f;
    const int  nt    = 4 * (qs + 1);
    const int  jmaxw = 4 * qs + (w >> 1);
    const bool oddw  = w & 1;

    issue(0);
    store_stage(0);
    __syncthreads();

    for (int j = 0; j < nt; ++j) {
      const int s = j & 1;
      const bool more = (j + 1 < nt);
      if (more) issue(j + 1);          // global loads fly under compute

      if (j <= jmaxw) {
        const bool full = oddw || (j < jmaxw);
        const u32* KB = lds + (size_t)s * 8192;
        const u32* VB = KB + 4096;
        const u32* kr0 = KB + (size_t)l31 * 64;
        const u32* kr1 = kr0 + 32 * 64;
        const int  swk = (l31 & 7) << 2;      // dword-col XOR

        // ---- QK^T (swapped): S^T[k][q] = K . Q^T ----
        f32x16 S0 = (f32x16)0.0f, S1 = (f32x16)0.0f;
        __builtin_amdgcn_s_setprio(1);
        #pragma unroll
        for (int ds = 0; ds < 8; ++ds) {
          int dc = (8 * ds + 4 * lg2) ^ swk;
          S0 = MFMA(ld_f16x8(kr0 + dc), qh[ds], S0);
          if (full) S1 = MFMA(ld_f16x8(kr1 + dc), qh[ds], S1);
        }
        __builtin_amdgcn_s_setprio(0);

        // ---- causal mask (diagonal tile only) ----
        if (j == jmaxw) {
          #pragma unroll
          for (int r = 0; r < 16; ++r) {
            int crow = (r & 3) + 8 * (r >> 2) + 4 * lg2;
            if (crow > l31) { if (oddw) S1[r] = -1e30f; else S0[r] = -1e30f; }
          }
        }

        // ---- online softmax (base-2), T13 deferred rescale ----
        float tm = S0[0];
        #pragma unroll
        for (int r = 1; r < 16; ++r) tm = fmaxf(tm, S0[r]);
        if (full) {
          #pragma unroll
          for (int r = 0; r < 16; ++r) tm = fmaxf(tm, S1[r]);
        }
        tm = fmaxf(tm, __shfl_xor(tm, 32));
        if (!__all(tm <= m2 + 8.0f)) {
          float m2n = fmaxf(m2, tm);
          float fac = exp2f(m2 - m2n);
          lsum *= fac;
          #pragma unroll
          for (int r = 0; r < 16; ++r) {
            int rq = (r & 3) + 8 * (r >> 2) + 4 * lg2;
            float fr = __shfl(fac, rq);
            O[0][r] *= fr; O[1][r] *= fr; O[2][r] *= fr; O[3][r] *= fr;
          }
          m2 = m2n;
        }
        u32 U[16];
        float ps = 0.0f;
        #pragma unroll
        for (int t = 0; t < 8; ++t) {
          float e0 = exp2f(S0[2 * t]     - m2);
          float e1 = exp2f(S0[2 * t + 1] - m2);
          U[t] = packh((_Float16)e0, (_Float16)e1);
          ps += e0 + e1;
        }
        if (full) {
          #pragma unroll
          for (int t = 0; t < 8; ++t) {
            float e0 = exp2f(S1[2 * t]     - m2);
            float e1 = exp2f(S1[2 * t + 1] - m2);
            U[8 + t] = packh((_Float16)e0, (_Float16)e1);
            ps += e0 + e1;
          }
        }
        ps += __shfl_xor(ps, 32);
        lsum += ps;

        // ---- PV: P fragments in-register via permlane32_swap ----
        __builtin_amdgcn_s_setprio(1);
        #pragma unroll
        for (int ks = 0; ks < 4; ++ks) {
          if (ks >= 2 && !full) continue;
          u32 a0 = U[4 * ks + 0], a1 = U[4 * ks + 1];
          u32 b0 = U[4 * ks + 2], b1 = U[4 * ks + 3];
          asm("v_permlane32_swap_b32 %0, %1" : "+v"(a0), "+v"(b0));
          asm("v_permlane32_swap_b32 %0, %1" : "+v"(a1), "+v"(b1));
          u32x4 t4; t4.x = a0; t4.y = a1; t4.z = b0; t4.w = b1;
          f16x8 pa = __builtin_bit_cast(f16x8, t4);
          int dcv = (8 * ks + 4 * lg2) ^ swk;
          #pragma unroll
          for (int n = 0; n < 4; ++n) {
            O[n] = MFMA(pa, ld_f16x8(VB + (size_t)(32 * n + l31) * 32 + dcv), O[n]);
          }
        }
        __builtin_amdgcn_s_setprio(0);
      }

      if (more) store_stage(s ^ 1);
      __syncthreads();
    }

    // ---------- epilogue ----------
    float inv = 1.0f / lsum;
    #pragma unroll
    for (int r = 0; r < 16; ++r) {
      int rq = (r & 3) + 8 * (r >> 2) + 4 * lg2;
      float fi = __shfl(inv, rq);
      float* orow = Og + (cbase + qs * 256 + w * 32 + rq) * 2048 + hoff + l31;
      orow[0]  = O[0][r] * fi;
      orow[32] = O[1][r] * fi;
      orow[64] = O[2][r] * fi;
      orow[96] = O[3][r] * fi;
    }
  }
}

// ================= fallback (R4/R6, passed) =================
#define KSTR 66
#define VSTR 34
#define KBUF (64 * KSTR)
#define STG  (KBUF + 128 * VSTR)

__global__ __launch_bounds__(512, 2)
void chunked_attn_fb(const float* __restrict__ Qg, const float* __restrict__ Kg,
                     const float* __restrict__ Vg, float* __restrict__ Og,
                     const float* __restrict__ tab) {
  __shared__ __align__(16) u32 lds[2 * STG];

  const int bx  = blockIdx.x;
  const int h   = bx & 15;
  const int p   = (bx >> 4) & 1;
  const int c   = (bx >> 5) & 3;
  const int b   = bx >> 7;
  const int tid = threadIdx.x;
  const int w   = tid >> 6;
  const int lane= tid & 63;
  const int l31 = lane & 31;
  const int lg2 = lane >> 5;

  const size_t cbase = (size_t)(b * Ll + c * 1024);
  const size_t hoff  = (size_t)h * 128;
  const int tb = c * 1024;

  f32x2 pk[8], pva[4], pvb[4];

  auto issue = [&](int j) {
    const float* kb_ = Kg + (cbase + (size_t)j * 64) * 2048 + hoff;
    const float* vb_ = Vg + (cbase + (size_t)j * 64) * 2048 + hoff;
    #pragma unroll
    for (int r = 0; r < 8; ++r)
      pk[r] = ld_f32x2(kb_ + (size_t)(8 * w + r) * 2048 + 2 * lane);
    #pragma unroll
    for (int rp = 0; rp < 4; ++rp) {
      const float* vr = vb_ + (size_t)(8 * w + 2 * rp) * 2048 + 2 * lane;
      pva[rp] = ld_f32x2(vr);
      pvb[rp] = ld_f32x2(vr + 2048);
    }
  };

  auto xform = [&](int j, int s) {
    u32* KB = lds + s * STG;
    u32* VB = KB + KBUF;
    const float* tbase = tab + (size_t)(tb + j * 64) * 128 + 4 * l31;
    f32x4 cs[8];
    #pragma unroll
    for (int r = 0; r < 8; ++r)
      cs[r] = ld_f32x4(tbase + (size_t)(8 * w + r) * 128);
    const float sgn = (lane < 32) ? -1.0f : 1.0f;
    #pragma unroll
    for (int r = 0; r < 8; ++r) {
      float a0 = pk[r].x, a1 = pk[r].y;
      float p0 = __shfl_xor(a0, 32), p1 = __shfl_xor(a1, 32);
      float o0 = a0 * cs[r].x + sgn * (p0 * cs[r].y);
      float o1 = a1 * cs[r].z + sgn * (p1 * cs[r].w);
      KB[(8 * w + r) * KSTR + lane] = packh((_Float16)o0, (_Float16)o1);
    }
    #pragma unroll
    for (int rp = 0; rp < 4; ++rp) {
      int kp = 4 * w + rp;
      VB[(2 * lane) * VSTR + kp]     = packh((_Float16)pva[rp].x, (_Float16)pvb[rp].x);
      VB[(2 * lane + 1) * VSTR + kp] = packh((_Float16)pva[rp].y, (_Float16)pvb[rp].y);
    }
  };

  #pragma unroll 1
  for (int sp = 0; sp < 2; ++sp) {
    const int qs = sp ? p : (3 - p);
    const int qrow = qs * 256 + w * 32 + l31;

    const float* qbase = Qg + (cbase + qrow) * 2048 + hoff;
    float xq[8][8];
    #pragma unroll
    for (int ds = 0; ds < 8; ++ds) {
      const float* ptr = qbase + ds * 16 + lg2 * 8;
      f32x4 v0 = ld_f32x4(ptr);
      f32x4 v1 = ld_f32x4(ptr + 4);
      xq[ds][0]=v0.x; xq[ds][1]=v0.y; xq[ds][2]=v0.z; xq[ds][3]=v0.w;
      xq[ds][4]=v1.x; xq[ds][5]=v1.y; xq[ds][6]=v1.z; xq[ds][7]=v1.w;
    }
    const float* trowq = tab + (size_t)(tb + qrow) * 128 + lg2 * 16;
    #pragma unroll
    for (int ds = 0; ds < 4; ++ds) {
      #pragma unroll
      for (int i2 = 0; i2 < 4; ++i2) {
        f32x4 cs = ld_f32x4(trowq + ds * 32 + i2 * 4);
        int i0 = 2 * i2;
        float a0 = xq[ds][i0],     b0 = xq[ds + 4][i0];
        xq[ds][i0]     = a0 * cs.x - b0 * cs.y;
        xq[ds + 4][i0] = b0 * cs.x + a0 * cs.y;
        float a1 = xq[ds][i0 + 1], b1 = xq[ds + 4][i0 + 1];
        xq[ds][i0 + 1]     = a1 * cs.z - b1 * cs.w;
        xq[ds + 4][i0 + 1] = b1 * cs.z + a1 * cs.w;
      }
    }
    f16x8 qh[8];
    #pragma unroll
    for (int ds = 0; ds < 8; ++ds)
      #pragma unroll
      for (int i = 0; i < 8; ++i)
        qh[ds][i] = (_Float16)(xq[ds][i] * QSCALE);

    f32x16 O[4];
    #pragma unroll
    for (int n = 0; n < 4; ++n) O[n] = (f32x16)0.0f;
    float m2 = -1e30f, lsum = 0.0f;
    const int  nt    = 4 * (qs + 1);
    const int  jmaxw = 4 * qs + (w >> 1);
    const bool oddw  = w & 1;

    issue(0);
    xform(0, 0);
    __syncthreads();

    for (int j = 0; j < nt; ++j) {
      const int s = j & 1;
      const bool more = (j + 1 < nt);
      if (more) issue(j + 1);

      if (j <= jmaxw) {
        const bool full = oddw || (j < jmaxw);
        const u32* KB = lds + s * STG;
        const u32* VB = KB + KBUF;
        const u32* kr0 = KB + (size_t)l31 * KSTR + lg2 * 4;
        const u32* kr1 = kr0 + (size_t)32 * KSTR;

        f32x16 S0 = (f32x16)0.0f, S1 = (f32x16)0.0f;
        __builtin_amdgcn_s_setprio(1);
        #pragma unroll
        for (int ds = 0; ds < 8; ++ds) {
          S0 = MFMA(ld_frag(kr0 + ds * 8), qh[ds], S0);
          if (full) S1 = MFMA(ld_frag(kr1 + ds * 8), qh[ds], S1);
        }
        __builtin_amdgcn_s_setprio(0);

        if (j == jmaxw) {
          #pragma unroll
          for (int r = 0; r < 16; ++r) {
            int crow = (r & 3) + 8 * (r >> 2) + 4 * lg2;
            if (crow > l31) { if (oddw) S1[r] = -1e30f; else S0[r] = -1e30f; }
          }
        }

        float tm = S0[0];
        #pragma unroll
        for (int r = 1; r < 16; ++r) tm = fmaxf(tm, S0[r]);
        if (full) {
          #pragma unroll
          for (int r = 0; r < 16; ++r) tm = fmaxf(tm, S1[r]);
        }
        tm = fmaxf(tm, __shfl_xor(tm, 32));
        if (!__all(tm <= m2 + 8.0f)) {
          float m2n = fmaxf(m2, tm);
          float fac = exp2f(m2 - m2n);
          lsum *= fac;
          #pragma unroll
          for (int r = 0; r < 16; ++r) {
            int rq = (r & 3) + 8 * (r >> 2) + 4 * lg2;
            float fr = __shfl(fac, rq);
            O[0][r] *= fr; O[1][r] *= fr; O[2][r] *= fr; O[3][r] *= fr;
          }
          m2 = m2n;
        }
        u32 U[16];
        float ps = 0.0f;
        #pragma unroll
        for (int t = 0; t < 8; ++t) {
          float e0 = exp2f(S0[2 * t]     - m2);
          float e1 = exp2f(S0[2 * t + 1] - m2);
          U[t] = packh((_Float16)e0, (_Float16)e1);
          ps += e0 + e1;
        }
        if (full) {
          #pragma unroll
          for (int t = 0; t < 8; ++t) {
            float e0 = exp2f(S1[2 * t]     - m2);
            float e1 = exp2f(S1[2 * t + 1] - m2);
            U[8 + t] = packh((_Float16)e0, (_Float16)e1);
            ps += e0 + e1;
          }
        }
        ps += __shfl_xor(ps, 32);
        lsum += ps;

        __builtin_amdgcn_s_setprio(1);
        #pragma unroll
        for (int ks = 0; ks < 4; ++ks) {
          if (ks >= 2 && !full) continue;
          u32 a0 = U[4 * ks + 0], a1 = U[4 * ks + 1];
          u32 b0 = U[4 * ks + 2], b1 = U[4 * ks + 3];
          asm("v_permlane32_swap_b32 %0, %1" : "+v"(a0), "+v"(b0));
          asm("v_permlane32_swap_b32 %0, %1" : "+v"(a1), "+v"(b1));
          u32x4 t4; t4.x = a0; t4.y = a1; t4.z = b0; t4.w = b1;
          f16x8 pa = __builtin_bit_cast(f16x8, t4);
          #pragma unroll
          for (int n = 0; n < 4; ++n) {
            const u32* vp = VB + (size_t)(32 * n + l31) * VSTR + 8 * ks + 4 * lg2;
            O[n] = MFMA(pa, ld_frag(vp), O[n]);
          }
        }
        __builtin_amdgcn_s_setprio(0);
      }

      if (more) xform(j + 1, s ^ 1);
      __syncthreads();
    }

    float inv = 1.0f / lsum;
    #pragma unroll
    for (int r = 0; r < 16; ++r) {
      int rq = (r & 3) + 8 * (r >> 2) + 4 * lg2;
      float fi = __shfl(inv, rq);
      float* orow = Og + (cbase + qs * 256 + w * 32 + rq) * 2048 + hoff + l31;
      orow[0]  = O[0][r] * fi;
      orow[32] = O[1][r] * fi;
      orow[64] = O[2][r] * fi;
      orow[96] = O[3][r] * fi;
    }
  }
}

extern "C" void kernel_launch(void* const* d_in, const int* in_sizes, int n_in,
                              void* d_out, int out_size, void* d_ws, size_t ws_size,
                              hipStream_t stream) {
  const float* q = (const float*)d_in[0];
  const float* k = (const float*)d_in[1];
  const float* v = (const float*)d_in[2];
  const int* start = (const int*)d_in[3];
  float* out = (float*)d_out;

  float* tab = (float*)d_ws;                          // 2 MB
  const size_t KH_OFFB = 2u * 1024 * 1024;            // 64 MB
  const size_t VT_OFFB = KH_OFFB + 64u * 1024 * 1024; // 64 MB
  const size_t NEED = VT_OFFB + 64u * 1024 * 1024;    // 130 MB total

  rope_table_k<<<dim3(1024), dim3(256), 0, stream>>>(start, tab);

  if (ws_size >= NEED) {
    u32* Kh = (u32*)((char*)d_ws + KH_OFFB);
    u32* VT = (u32*)((char*)d_ws + VT_OFFB);
    prep_merged_kernel<<<dim3(69632), dim3(256), 0, stream>>>(k, v, tab, Kh, VT);
    attn_f16_k<<<dim3(512), dim3(512), 0, stream>>>(q, Kh, VT, out, tab);
  } else {
    chunked_attn_fb<<<dim3(512), dim3(512), 0, stream>>>(q, k, v, out, tab);
  }
}

// Round 13
// 269.907 us; speedup vs baseline: 1.3487x; 1.0008x over previous
//
#include <hip/hip_runtime.h>

// ChunkedSelfAttention (RoPE + per-chunk causal SDPA), MI355X gfx950.
// R13: R12 verbatim (best: 270us total) + two proven VALU cuts in the attn
// softmax: cvt_pkrtz P-packing (R7/R11-validated) and parallel fmax tree
// (R11-validated). No other changes.

typedef __attribute__((ext_vector_type(2)))  float     f32x2;
typedef __attribute__((ext_vector_type(4)))  float     f32x4;
typedef __attribute__((ext_vector_type(16))) float     f32x16;
typedef __attribute__((ext_vector_type(8)))  _Float16  f16x8;
typedef unsigned int   u32;
typedef unsigned short u16;
typedef __attribute__((ext_vector_type(4))) unsigned int u32x4;

#define MFMA(a, b, c) __builtin_amdgcn_mfma_f32_32x32x16_f16(a, b, c, 0, 0, 0)

constexpr int Ll = 4096;
constexpr float QSCALE = 0.08838834764831845f * 1.4426950408889634f; // 1/sqrt(128)*log2(e)

__device__ __forceinline__ f32x4 ld_f32x4(const void* p) { f32x4 v; __builtin_memcpy(&v, p, 16); return v; }
__device__ __forceinline__ f32x2 ld_f32x2(const void* p) { f32x2 v; __builtin_memcpy(&v, p, 8);  return v; }
__device__ __forceinline__ u32x4 ld_u32x4(const void* p) { u32x4 v; __builtin_memcpy(&v, p, 16); return v; }
__device__ __forceinline__ void  st_u32x4(void* p, u32x4 v) { __builtin_memcpy(p, &v, 16); }
__device__ __forceinline__ f16x8 ld_f16x8(const void* p) { f16x8 v; __builtin_memcpy(&v, p, 16); return v; }
__device__ __forceinline__ f16x8 ld_frag(const u32* dwp) {
  f16x8 v;
  __builtin_memcpy(&v, dwp, 8);
  __builtin_memcpy(((char*)&v) + 8, dwp + 2, 8);
  return v;
}
__device__ __forceinline__ u32 packh(_Float16 a, _Float16 b) {
  return (u32)__builtin_bit_cast(u16, a) | ((u32)__builtin_bit_cast(u16, b) << 16);
}
__device__ __forceinline__ u32 pkrtz(float a, float b) {
  auto v = __builtin_amdgcn_cvt_pkrtz(a, b);
  u32 r; __builtin_memcpy(&r, &v, 4); return r;
}

// ---- cos/sin table (verbatim R6) ----
__global__ void rope_table_k(const int* __restrict__ startp, float* __restrict__ tab) {
  int idx = blockIdx.x * 256 + threadIdx.x;
  int t = idx >> 6, hid = idx & 63;
  float a = (float)hid * (-0.14391156831212878f);
  float invf = expf(a);
  float ang = (float)(t + startp[0]) * invf;
  tab[2 * idx]     = cosf(ang);
  tab[2 * idx + 1] = sinf(ang);
}

// ---- merged prepass (verbatim R12) ----
__global__ __launch_bounds__(256)
void prep_merged_kernel(const float* __restrict__ Kg, const float* __restrict__ Vg,
                        const float* __restrict__ tab, u32* __restrict__ Kh,
                        u32* __restrict__ VT) {
  __shared__ __align__(16) u32 tile[4096];
  const int bx = blockIdx.x;
  if (bx < 65536) {
    const int R    = bx * 4 + (threadIdx.x >> 6);
    const int lane = threadIdx.x & 63;
    const int h  = R & 15;
    const int bt = R >> 4;
    const int b  = bt >> 12;
    const int t  = bt & 4095;
    const int c  = t >> 10;
    const int j  = (t >> 6) & 15;
    const int row = t & 63;
    const int GID = (b * 4 + c) * 16 + h;
    const int sw  = (row & 7) << 4;
    const int dc  = ((4 * lane) ^ sw) >> 1;
    f32x2 a = ld_f32x2(Kg + (size_t)R * 128 + dc);
    float p0 = __shfl_xor(a.x, 32);
    float p1 = __shfl_xor(a.y, 32);
    f32x4 cs = ld_f32x4(tab + (size_t)t * 128 + 2 * (dc & 63));
    const float sgn = (dc < 64) ? -1.0f : 1.0f;
    float o0 = a.x * cs.x + sgn * (p0 * cs.y);
    float o1 = a.y * cs.z + sgn * (p1 * cs.w);
    Kh[((size_t)(GID * 16 + j) * 64 + row) * 64 + lane] = packh((_Float16)o0, (_Float16)o1);
  } else {
    const int gj  = bx - 65536;
    const int GID = gj >> 4, j = gj & 15;
    const int h = GID & 15, c = (GID >> 4) & 3, b = GID >> 6;
    const int tid = threadIdx.x;
    const size_t rowbase = ((size_t)(b * 4096 + c * 1024 + j * 64)) * 16 + h;
    const int k  = tid >> 2;
    const int dq = tid & 3;
    u16* t16 = (u16*)tile;
    #pragma unroll
    for (int it = 0; it < 8; ++it) {
      int dv0 = dq * 4 + 16 * it;
      f32x4 v4 = ld_f32x4(Vg + (rowbase + (size_t)k * 16) * 128 + dv0);
      #pragma unroll
      for (int u = 0; u < 4; ++u) {
        int dv = dv0 + u;
        int ci = k ^ ((dv & 7) << 3);
        t16[dv * 64 + ci] = __builtin_bit_cast(u16, (_Float16)v4[u]);
      }
    }
    __syncthreads();
    const u32* tsrc = tile + 16 * tid;
    u32* dst = VT + (size_t)gj * 4096 + 16 * tid;
    #pragma unroll
    for (int u = 0; u < 4; ++u) st_u32x4(dst + 4 * u, ld_u32x4(tsrc + 4 * u));
  }
}

// ================= main attention (R6 skeleton + pkrtz + fmax tree) =================
__global__ __launch_bounds__(512, 2)
void attn_f16_k(const float* __restrict__ Qg, const u32* __restrict__ Kh,
                const u32* __restrict__ VT, float* __restrict__ Og,
                const float* __restrict__ tab) {
  __shared__ __align__(16) u32 lds[2 * 8192];   // 64 KB, double-buffered

  const int bx  = blockIdx.x;
  const int h   = bx & 15;
  const int p   = (bx >> 4) & 1;
  const int c   = (bx >> 5) & 3;
  const int b   = bx >> 7;
  const int tid = threadIdx.x;
  const int w   = tid >> 6;
  const int lane= tid & 63;
  const int l31 = lane & 31;
  const int lg2 = lane >> 5;

  const size_t cbase = (size_t)(b * Ll + c * 1024);
  const size_t hoff  = (size_t)h * 128;
  const int tb  = c * 1024;
  const int GID = (b * 4 + c) * 16 + h;
  const u32* khg = Kh + (size_t)GID * 16 * 4096;
  const u32* vtg = VT + (size_t)GID * 16 * 4096;

  u32x4 stg[4];
  auto issue = [&](int j) {
    #pragma unroll
    for (int i = 0; i < 4; ++i) {
      int ch = w + 8 * i;                // 32 chunks of 1 KB: 0..15 K, 16..31 VT
      const u32* src = (ch < 16) ? (khg + (size_t)j * 4096 + ch * 256 + 4 * lane)
                                 : (vtg + (size_t)j * 4096 + (ch - 16) * 256 + 4 * lane);
      stg[i] = ld_u32x4(src);
    }
  };
  auto store_stage = [&](int s) {
    u32* dst0 = lds + (size_t)s * 8192;
    #pragma unroll
    for (int i = 0; i < 4; ++i) {
      int ch = w + 8 * i;
      st_u32x4(dst0 + ch * 256 + 4 * lane, stg[i]);
    }
  };

  auto vmax16 = [](const f32x16& S) {
    float a0 = fmaxf(S[0], S[1]),   a1 = fmaxf(S[2], S[3]);
    float a2 = fmaxf(S[4], S[5]),   a3 = fmaxf(S[6], S[7]);
    float a4 = fmaxf(S[8], S[9]),   a5 = fmaxf(S[10], S[11]);
    float a6 = fmaxf(S[12], S[13]), a7 = fmaxf(S[14], S[15]);
    float b0 = fmaxf(a0, a1), b1 = fmaxf(a2, a3);
    float b2 = fmaxf(a4, a5), b3 = fmaxf(a6, a7);
    return fmaxf(fmaxf(b0, b1), fmaxf(b2, b3));
  };

  #pragma unroll 1
  for (int sp = 0; sp < 2; ++sp) {
    const int qs = sp ? p : (3 - p);            // heavy strip first
    const int qrow = qs * 256 + w * 32 + l31;

    // ---------- Q prologue: load f32, rope, scale, f16 ----------
    const float* qbase = Qg + (cbase + qrow) * 2048 + hoff;
    float xq[8][8];
    #pragma unroll
    for (int ds = 0; ds < 8; ++ds) {
      const float* ptr = qbase + ds * 16 + lg2 * 8;
      f32x4 v0 = ld_f32x4(ptr);
      f32x4 v1 = ld_f32x4(ptr + 4);
      xq[ds][0]=v0.x; xq[ds][1]=v0.y; xq[ds][2]=v0.z; xq[ds][3]=v0.w;
      xq[ds][4]=v1.x; xq[ds][5]=v1.y; xq[ds][6]=v1.z; xq[ds][7]=v1.w;
    }
    const float* trowq = tab + (size_t)(tb + qrow) * 128 + lg2 * 16;
    #pragma unroll
    for (int ds = 0; ds < 4; ++ds) {
      #pragma unroll
      for (int i2 = 0; i2 < 4; ++i2) {
        f32x4 cs = ld_f32x4(trowq + ds * 32 + i2 * 4);
        int i0 = 2 * i2;
        float a0 = xq[ds][i0],     b0 = xq[ds + 4][i0];
        xq[ds][i0]     = a0 * cs.x - b0 * cs.y;
        xq[ds + 4][i0] = b0 * cs.x + a0 * cs.y;
        float a1 = xq[ds][i0 + 1], b1 = xq[ds + 4][i0 + 1];
        xq[ds][i0 + 1]     = a1 * cs.z - b1 * cs.w;
        xq[ds + 4][i0 + 1] = b1 * cs.z + a1 * cs.w;
      }
    }
    f16x8 qh[8];
    #pragma unroll
    for (int ds = 0; ds < 8; ++ds)
      #pragma unroll
      for (int i = 0; i < 8; ++i)
        qh[ds][i] = (_Float16)(xq[ds][i] * QSCALE);

    // ---------- state ----------
    f32x16 O[4];
    #pragma unroll
    for (int n = 0; n < 4; ++n) O[n] = (f32x16)0.0f;
    float m2 = -1e30f, lsum = 0.0f;
    const int  nt    = 4 * (qs + 1);
    const int  jmaxw = 4 * qs + (w >> 1);
    const bool oddw  = w & 1;

    issue(0);
    store_stage(0);
    __syncthreads();

    for (int j = 0; j < nt; ++j) {
      const int s = j & 1;
      const bool more = (j + 1 < nt);
      if (more) issue(j + 1);          // global loads fly under compute

      if (j <= jmaxw) {
        const bool full = oddw || (j < jmaxw);
        const u32* KB = lds + (size_t)s * 8192;
        const u32* VB = KB + 4096;
        const u32* kr0 = KB + (size_t)l31 * 64;
        const u32* kr1 = kr0 + 32 * 64;
        const int  swk = (l31 & 7) << 2;      // dword-col XOR

        // ---- QK^T (swapped): S^T[k][q] = K . Q^T ----
        f32x16 S0 = (f32x16)0.0f, S1 = (f32x16)0.0f;
        __builtin_amdgcn_s_setprio(1);
        #pragma unroll
        for (int ds = 0; ds < 8; ++ds) {
          int dc = (8 * ds + 4 * lg2) ^ swk;
          S0 = MFMA(ld_f16x8(kr0 + dc), qh[ds], S0);
          if (full) S1 = MFMA(ld_f16x8(kr1 + dc), qh[ds], S1);
        }
        __builtin_amdgcn_s_setprio(0);

        // ---- causal mask (diagonal tile only) ----
        if (j == jmaxw) {
          #pragma unroll
          for (int r = 0; r < 16; ++r) {
            int crow = (r & 3) + 8 * (r >> 2) + 4 * lg2;
            if (crow > l31) { if (oddw) S1[r] = -1e30f; else S0[r] = -1e30f; }
          }
        }

        // ---- online softmax (base-2), T13 deferred rescale ----
        float tm = vmax16(S0);
        if (full) tm = fmaxf(tm, vmax16(S1));
        tm = fmaxf(tm, __shfl_xor(tm, 32));
        if (!__all(tm <= m2 + 8.0f)) {
          float m2n = fmaxf(m2, tm);
          float fac = exp2f(m2 - m2n);
          lsum *= fac;
          #pragma unroll
          for (int r = 0; r < 16; ++r) {
            int rq = (r & 3) + 8 * (r >> 2) + 4 * lg2;
            float fr = __shfl(fac, rq);
            O[0][r] *= fr; O[1][r] *= fr; O[2][r] *= fr; O[3][r] *= fr;
          }
          m2 = m2n;
        }
        u32 U[16];
        float ps = 0.0f;
        #pragma unroll
        for (int t = 0; t < 8; ++t) {
          float e0 = exp2f(S0[2 * t]     - m2);
          float e1 = exp2f(S0[2 * t + 1] - m2);
          U[t] = pkrtz(e0, e1);
          ps += e0 + e1;
        }
        if (full) {
          #pragma unroll
          for (int t = 0; t < 8; ++t) {
            float e0 = exp2f(S1[2 * t]     - m2);
            float e1 = exp2f(S1[2 * t + 1] - m2);
            U[8 + t] = pkrtz(e0, e1);
            ps += e0 + e1;
          }
        }
        ps += __shfl_xor(ps, 32);
        lsum += ps;

        // ---- PV: P fragments in-register via permlane32_swap ----
        __builtin_amdgcn_s_setprio(1);
        #pragma unroll
        for (int ks = 0; ks < 4; ++ks) {
          if (ks >= 2 && !full) continue;
          u32 a0 = U[4 * ks + 0], a1 = U[4 * ks + 1];
          u32 b0 = U[4 * ks + 2], b1 = U[4 * ks + 3];
          asm("v_permlane32_swap_b32 %0, %1" : "+v"(a0), "+v"(b0));
          asm("v_permlane32_swap_b32 %0, %1" : "+v"(a1), "+v"(b1));
          u32x4 t4; t4.x = a0; t4.y = a1; t4.z = b0; t4.w = b1;
          f16x8 pa = __builtin_bit_cast(f16x8, t4);
          int dcv = (8 * ks + 4 * lg2) ^ swk;
          #pragma unroll
          for (int n = 0; n < 4; ++n) {
            O[n] = MFMA(pa, ld_f16x8(VB + (size_t)(32 * n + l31) * 32 + dcv), O[n]);
          }
        }
        __builtin_amdgcn_s_setprio(0);
      }

      if (more) store_stage(s ^ 1);
      __syncthreads();
    }

    // ---------- epilogue ----------
    float inv = 1.0f / lsum;
    #pragma unroll
    for (int r = 0; r < 16; ++r) {
      int rq = (r & 3) + 8 * (r >> 2) + 4 * lg2;
      float fi = __shfl(inv, rq);
      float* orow = Og + (cbase + qs * 256 + w * 32 + rq) * 2048 + hoff + l31;
      orow[0]  = O[0][r] * fi;
      orow[32] = O[1][r] * fi;
      orow[64] = O[2][r] * fi;
      orow[96] = O[3][r] * fi;
    }
  }
}

// ================= fallback (R4/R6, passed) =================
#define KSTR 66
#define VSTR 34
#define KBUF (64 * KSTR)
#define STG  (KBUF + 128 * VSTR)

__global__ __launch_bounds__(512, 2)
void chunked_attn_fb(const float* __restrict__ Qg, const float* __restrict__ Kg,
                     const float* __restrict__ Vg, float* __restrict__ Og,
                     const float* __restrict__ tab) {
  __shared__ __align__(16) u32 lds[2 * STG];

  const int bx  = blockIdx.x;
  const int h   = bx & 15;
  const int p   = (bx >> 4) & 1;
  const int c   = (bx >> 5) & 3;
  const int b   = bx >> 7;
  const int tid = threadIdx.x;
  const int w   = tid >> 6;
  const int lane= tid & 63;
  const int l31 = lane & 31;
  const int lg2 = lane >> 5;

  const size_t cbase = (size_t)(b * Ll + c * 1024);
  const size_t hoff  = (size_t)h * 128;
  const int tb = c * 1024;

  f32x2 pk[8], pva[4], pvb[4];

  auto issue = [&](int j) {
    const float* kb_ = Kg + (cbase + (size_t)j * 64) * 2048 + hoff;
    const float* vb_ = Vg + (cbase + (size_t)j * 64) * 2048 + hoff;
    #pragma unroll
    for (int r = 0; r < 8; ++r)
      pk[r] = ld_f32x2(kb_ + (size_t)(8 * w + r) * 2048 + 2 * lane);
    #pragma unroll
    for (int rp = 0; rp < 4; ++rp) {
      const float* vr = vb_ + (size_t)(8 * w + 2 * rp) * 2048 + 2 * lane;
      pva[rp] = ld_f32x2(vr);
      pvb[rp] = ld_f32x2(vr + 2048);
    }
  };

  auto xform = [&](int j, int s) {
    u32* KB = lds + s * STG;
    u32* VB = KB + KBUF;
    const float* tbase = tab + (size_t)(tb + j * 64) * 128 + 4 * l31;
    f32x4 cs[8];
    #pragma unroll
    for (int r = 0; r < 8; ++r)
      cs[r] = ld_f32x4(tbase + (size_t)(8 * w + r) * 128);
    const float sgn = (lane < 32) ? -1.0f : 1.0f;
    #pragma unroll
    for (int r = 0; r < 8; ++r) {
      float a0 = pk[r].x, a1 = pk[r].y;
      float p0 = __shfl_xor(a0, 32), p1 = __shfl_xor(a1, 32);
      float o0 = a0 * cs[r].x + sgn * (p0 * cs[r].y);
      float o1 = a1 * cs[r].z + sgn * (p1 * cs[r].w);
      KB[(8 * w + r) * KSTR + lane] = packh((_Float16)o0, (_Float16)o1);
    }
    #pragma unroll
    for (int rp = 0; rp < 4; ++rp) {
      int kp = 4 * w + rp;
      VB[(2 * lane) * VSTR + kp]     = packh((_Float16)pva[rp].x, (_Float16)pvb[rp].x);
      VB[(2 * lane + 1) * VSTR + kp] = packh((_Float16)pva[rp].y, (_Float16)pvb[rp].y);
    }
  };

  #pragma unroll 1
  for (int sp = 0; sp < 2; ++sp) {
    const int qs = sp ? p : (3 - p);
    const int qrow = qs * 256 + w * 32 + l31;

    const float* qbase = Qg + (cbase + qrow) * 2048 + hoff;
    float xq[8][8];
    #pragma unroll
    for (int ds = 0; ds < 8; ++ds) {
      const float* ptr = qbase + ds * 16 + lg2 * 8;
      f32x4 v0 = ld_f32x4(ptr);
      f32x4 v1 = ld_f32x4(ptr + 4);
      xq[ds][0]=v0.x; xq[ds][1]=v0.y; xq[ds][2]=v0.z; xq[ds][3]=v0.w;
      xq[ds][4]=v1.x; xq[ds][5]=v1.y; xq[ds][6]=v1.z; xq[ds][7]=v1.w;
    }
    const float* trowq = tab + (size_t)(tb + qrow) * 128 + lg2 * 16;
    #pragma unroll
    for (int ds = 0; ds < 4; ++ds) {
      #pragma unroll
      for (int i2 = 0; i2 < 4; ++i2) {
        f32x4 cs = ld_f32x4(trowq + ds * 32 + i2 * 4);
        int i0 = 2 * i2;
        float a0 = xq[ds][i0],     b0 = xq[ds + 4][i0];
        xq[ds][i0]     = a0 * cs.x - b0 * cs.y;
        xq[ds + 4][i0] = b0 * cs.x + a0 * cs.y;
        float a1 = xq[ds][i0 + 1], b1 = xq[ds + 4][i0 + 1];
        xq[ds][i0 + 1]     = a1 * cs.z - b1 * cs.w;
        xq[ds + 4][i0 + 1] = b1 * cs.z + a1 * cs.w;
      }
    }
    f16x8 qh[8];
    #pragma unroll
    for (int ds = 0; ds < 8; ++ds)
      #pragma unroll
      for (int i = 0; i < 8; ++i)
        qh[ds][i] = (_Float16)(xq[ds][i] * QSCALE);

    f32x16 O[4];
    #pragma unroll
    for (int n = 0; n < 4; ++n) O[n] = (f32x16)0.0f;
    float m2 = -1e30f, lsum = 0.0f;
    const int  nt    = 4 * (qs + 1);
    const int  jmaxw = 4 * qs + (w >> 1);
    const bool oddw  = w & 1;

    issue(0);
    xform(0, 0);
    __syncthreads();

    for (int j = 0; j < nt; ++j) {
      const int s = j & 1;
      const bool more = (j + 1 < nt);
      if (more) issue(j + 1);

      if (j <= jmaxw) {
        const bool full = oddw || (j < jmaxw);
        const u32* KB = lds + s * STG;
        const u32* VB = KB + KBUF;
        const u32* kr0 = KB + (size_t)l31 * KSTR + lg2 * 4;
        const u32* kr1 = kr0 + (size_t)32 * KSTR;

        f32x16 S0 = (f32x16)0.0f, S1 = (f32x16)0.0f;
        __builtin_amdgcn_s_setprio(1);
        #pragma unroll
        for (int ds = 0; ds < 8; ++ds) {
          S0 = MFMA(ld_frag(kr0 + ds * 8), qh[ds], S0);
          if (full) S1 = MFMA(ld_frag(kr1 + ds * 8), qh[ds], S1);
        }
        __builtin_amdgcn_s_setprio(0);

        if (j == jmaxw) {
          #pragma unroll
          for (int r = 0; r < 16; ++r) {
            int crow = (r & 3) + 8 * (r >> 2) + 4 * lg2;
            if (crow > l31) { if (oddw) S1[r] = -1e30f; else S0[r] = -1e30f; }
          }
        }

        float tm = S0[0];
        #pragma unroll
        for (int r = 1; r < 16; ++r) tm = fmaxf(tm, S0[r]);
        if (full) {
          #pragma unroll
          for (int r = 0; r < 16; ++r) tm = fmaxf(tm, S1[r]);
        }
        tm = fmaxf(tm, __shfl_xor(tm, 32));
        if (!__all(tm <= m2 + 8.0f)) {
          float m2n = fmaxf(m2, tm);
          float fac = exp2f(m2 - m2n);
          lsum *= fac;
          #pragma unroll
          for (int r = 0; r < 16; ++r) {
            int rq = (r & 3) + 8 * (r >> 2) + 4 * lg2;
            float fr = __shfl(fac, rq);
            O[0][r] *= fr; O[1][r] *= fr; O[2][r] *= fr; O[3][r] *= fr;
          }
          m2 = m2n;
        }
        u32 U[16];
        float ps = 0.0f;
        #pragma unroll
        for (int t = 0; t < 8; ++t) {
          float e0 = exp2f(S0[2 * t]     - m2);
          float e1 = exp2f(S0[2 * t + 1] - m2);
          U[t] = packh((_Float16)e0, (_Float16)e1);
          ps += e0 + e1;
        }
        if (full) {
          #pragma unroll
          for (int t = 0; t < 8; ++t) {
            float e0 = exp2f(S1[2 * t]     - m2);
            float e1 = exp2f(S1[2 * t + 1] - m2);
            U[8 + t] = packh((_Float16)e0, (_Float16)e1);
            ps += e0 + e1;
          }
        }
        ps += __shfl_xor(ps, 32);
        lsum += ps;

        __builtin_amdgcn_s_setprio(1);
        #pragma unroll
        for (int ks = 0; ks < 4; ++ks) {
          if (ks >= 2 && !full) continue;
          u32 a0 = U[4 * ks + 0], a1 = U[4 * ks + 1];
          u32 b0 = U[4 * ks + 2], b1 = U[4 * ks + 3];
          asm("v_permlane32_swap_b32 %0, %1" : "+v"(a0), "+v"(b0));
          asm("v_permlane32_swap_b32 %0, %1" : "+v"(a1), "+v"(b1));
          u32x4 t4; t4.x = a0; t4.y = a1; t4.z = b0; t4.w = b1;
          f16x8 pa = __builtin_bit_cast(f16x8, t4);
          #pragma unroll
          for (int n = 0; n < 4; ++n) {
            const u32* vp = VB + (size_t)(32 * n + l31) * VSTR + 8 * ks + 4 * lg2;
            O[n] = MFMA(pa, ld_frag(vp), O[n]);
          }
        }
        __builtin_amdgcn_s_setprio(0);
      }

      if (more) xform(j + 1, s ^ 1);
      __syncthreads();
    }

    float inv = 1.0f / lsum;
    #pragma unroll
    for (int r = 0; r < 16; ++r) {
      int rq = (r & 3) + 8 * (r >> 2) + 4 * lg2;
      float fi = __shfl(inv, rq);
      float* orow = Og + (cbase + qs * 256 + w * 32 + rq) * 2048 + hoff + l31;
      orow[0]  = O[0][r] * fi;
      orow[32] = O[1][r] * fi;
      orow[64] = O[2][r] * fi;
      orow[96] = O[3][r] * fi;
    }
  }
}

extern "C" void kernel_launch(void* const* d_in, const int* in_sizes, int n_in,
                              void* d_out, int out_size, void* d_ws, size_t ws_size,
                              hipStream_t stream) {
  const float* q = (const float*)d_in[0];
  const float* k = (const float*)d_in[1];
  const float* v = (const float*)d_in[2];
  const int* start = (const int*)d_in[3];
  float* out = (float*)d_out;

  float* tab = (float*)d_ws;                          // 2 MB
  const size_t KH_OFFB = 2u * 1024 * 1024;            // 64 MB
  const size_t VT_OFFB = KH_OFFB + 64u * 1024 * 1024; // 64 MB
  const size_t NEED = VT_OFFB + 64u * 1024 * 1024;    // 130 MB total

  rope_table_k<<<dim3(1024), dim3(256), 0, stream>>>(start, tab);

  if (ws_size >= NEED) {
    u32* Kh = (u32*)((char*)d_ws + KH_OFFB);
    u32* VT = (u32*)((char*)d_ws + VT_OFFB);
    prep_merged_kernel<<<dim3(69632), dim3(256), 0, stream>>>(k, v, tab, Kh, VT);
    attn_f16_k<<<dim3(512), dim3(512), 0, stream>>>(q, Kh, VT, out, tab);
  } else {
    chunked_attn_fb<<<dim3(512), dim3(512), 0, stream>>>(q, k, v, out, tab);
  }
}